// Round 8
// baseline (644.240 us; speedup 1.0000x reference)
//
#include <hip/hip_runtime.h>
#include <hip/hip_bf16.h>

typedef __hip_bfloat16 bf16;
typedef __attribute__((ext_vector_type(8))) short bh8;      // 8 x bf16 bits
typedef __attribute__((ext_vector_type(4))) short bh4;      // 4 x bf16 bits
typedef __attribute__((ext_vector_type(4))) float f32x4;

#define CDIM 512
#define NDIM 4096
#define HIDD 2048
#define BATCH 8

__device__ __forceinline__ float bf2f(short s) {
    union { unsigned u; float f; } c; c.u = ((unsigned)(unsigned short)s) << 16; return c.f;
}
__device__ __forceinline__ short f2bf(float f) {
    union { __hip_bfloat16 h; short s; } c; c.h = __float2bfloat16(f); return c.s;
}
__device__ __forceinline__ float wsum(float v) {
#pragma unroll
    for (int o = 32; o; o >>= 1) v += __shfl_xor(v, o);
    return v;
}
__device__ __forceinline__ float wmax(float v) {
#pragma unroll
    for (int o = 32; o; o >>= 1) v = fmaxf(v, __shfl_xor(v, o));
    return v;
}

#define GLL(g, l) __builtin_amdgcn_global_load_lds( \
    (const __attribute__((address_space(1))) unsigned int*)(g), \
    (__attribute__((address_space(3))) unsigned int*)(l), 16, 0, 0)

// XCD-aware bijective block swizzle (T1): contiguous work-chunk per XCD.
// Requires nwg % 8 == 0 (all our grids satisfy this).
__device__ __forceinline__ void xcd_swz(int& bx, int& by, int& bz) {
    const int gx = gridDim.x, gy = gridDim.y;
    const int nwg = gx * gy * gridDim.z;
    int lid = blockIdx.x + gx * (blockIdx.y + gy * blockIdx.z);
    const int cpx = nwg >> 3;
    int swz = (lid & 7) * cpx + (lid >> 3);
    bx = swz % gx; swz /= gx;
    by = swz % gy;
    bz = swz / gy;
}

// ---------------------------------------------------------------- GEMM (NT)
// C[M,N] = A(M,K) @ Bt(N,K)^T, row-major bf16, fp32 accum. TMx128 tile, BK=64.
// LDS tiles XOR-swizzled (pre-swizzled GLL source + swizzled fragment read).
enum { EP_QEXP = 0, EP_BF16_BROW = 1, EP_ATTN = 3, EP_BF16_BCOL = 4, EP_OUT = 5, EP_QKV = 6 };

template<int MODE, int TM>
__global__ __launch_bounds__(256)
void gemm_bt(const bf16* __restrict__ A, int lda, long sA,
             const bf16* __restrict__ Bt, int ldb, long sB,
             void* __restrict__ Cp, int ldc, long sC, int K,
             const float* __restrict__ bias,
             const void* __restrict__ aux1, long sAux1,
             const void* __restrict__ aux2, long sAux2)
{
    constexpr int MF = TM / 32;                 // A-frags per wave; also A-chunks/thread
    __shared__ __align__(16) bf16 As[TM * 64];
    __shared__ __align__(16) bf16 Bs[128 * 64];
    int bx, by, bz;
    xcd_swz(bx, by, bz);
    const bf16* Ab = A + (long)bz * sA + (long)by * TM * lda;
    const bf16* Bb = Bt + (long)bz * sB + (long)bx * 128 * ldb;
    const int t = threadIdx.x, lane = t & 63, wid = t >> 6;
    const int wm = wid >> 1, wn = wid & 1, lg = lane >> 4, lr = lane & 15;

    f32x4 acc[MF][4];
#pragma unroll
    for (int m = 0; m < MF; ++m)
#pragma unroll
        for (int n = 0; n < 4; ++n) acc[m][n] = (f32x4){0.f, 0.f, 0.f, 0.f};

    for (int kt = 0; kt < K; kt += 64) {
#pragma unroll
        for (int i = 0; i < MF; ++i) {
            const int ch = i * 256 + t;
            const int row = ch >> 3;
            const int cs = (ch & 7) ^ (row & 7);    // pre-swizzled source chunk
            GLL(Ab + (long)row * lda + kt + (cs << 3), (char*)As + i * 4096 + wid * 1024);
        }
#pragma unroll
        for (int i = 0; i < 4; ++i) {
            const int ch = i * 256 + t;
            const int row = ch >> 3;
            const int cs = (ch & 7) ^ (row & 7);
            GLL(Bb + (long)row * ldb + kt + (cs << 3), (char*)Bs + i * 4096 + wid * 1024);
        }
        __syncthreads();
#pragma unroll
        for (int kk = 0; kk < 2; ++kk) {
            bh8 af[MF], bfv[4];
#pragma unroll
            for (int m = 0; m < MF; ++m) {
                const int row = wm * (TM / 2) + m * 16 + lr;
                const int kc = (kk * 4 + lg) ^ (row & 7);
                af[m] = *(const bh8*)(As + row * 64 + kc * 8);
            }
#pragma unroll
            for (int n = 0; n < 4; ++n) {
                const int row = wn * 64 + n * 16 + lr;
                const int kc = (kk * 4 + lg) ^ (row & 7);
                bfv[n] = *(const bh8*)(Bs + row * 64 + kc * 8);
            }
#pragma unroll
            for (int m = 0; m < MF; ++m)
#pragma unroll
                for (int n = 0; n < 4; ++n)
                    acc[m][n] = __builtin_amdgcn_mfma_f32_16x16x32_bf16(af[m], bfv[n], acc[m][n], 0, 0, 0);
        }
        __syncthreads();
    }

    const int gr0 = by * TM + wm * (TM / 2);
    const int gc0 = bx * 128 + wn * 64;
#pragma unroll
    for (int m = 0; m < MF; ++m) {
#pragma unroll
        for (int n = 0; n < 4; ++n) {
            const int gc = gc0 + n * 16 + lr;
#pragma unroll
            for (int r = 0; r < 4; ++r) {
                const int gr = gr0 + m * 16 + lg * 4 + r;
                float v = acc[m][n][r];
                if constexpr (MODE == EP_QKV) {
                    // fused conv q/k/v: rows 0-511 -> qe (exp), 512-1023 -> kb, 1024-1535 -> vb
                    const int which = gr >> 9, grl = gr & 511;   // wave-uniform per block
                    const float vb_ = v + bias[gr];
                    if (which == 0)
                        ((bf16*)Cp + (long)bz * sC)[(long)grl * ldc + gc] = __float2bfloat16(expf(vb_));
                    else if (which == 1)
                        ((bf16*)aux1 + (long)bz * sC)[(long)grl * ldc + gc] = __float2bfloat16(vb_);
                    else
                        ((bf16*)aux2 + (long)bz * sC)[(long)grl * ldc + gc] = __float2bfloat16(vb_);
                } else if constexpr (MODE == EP_QEXP) {
                    ((bf16*)Cp + (long)bz * sC)[(long)gr * ldc + gc] = __float2bfloat16(expf(v + bias[gr]));
                } else if constexpr (MODE == EP_BF16_BROW) {
                    ((bf16*)Cp + (long)bz * sC)[(long)gr * ldc + gc] = __float2bfloat16(v + bias[gr]);
                } else if constexpr (MODE == EP_ATTN) {
                    // shortcut from xbT (bf16, (N,C) row-major -> coalesced)
                    const bf16* xg = (const bf16*)aux1 + (long)bz * sAux1;
                    const float* zg = (const float*)aux2 + (long)bz * sAux2;   // z[b] (N)
                    ((float*)Cp + (long)bz * sC)[(long)gr * ldc + gc] =
                        zg[gr] * v + bf2f(*(const short*)(xg + (long)gr * 512 + gc));
                } else if constexpr (MODE == EP_BF16_BCOL) {
                    ((bf16*)Cp + (long)bz * sC)[(long)gr * ldc + gc] = __float2bfloat16(v + bias[gc]);
                } else { // EP_OUT: out = acc + bias[col] + out (in-place residual)
                    float* op = (float*)Cp;
                    const long idx = (long)gr * ldc + gc;
                    op[idx] = v + bias[gc] + ((const float*)aux1)[idx];
                }
            }
        }
    }
}

// ---------------------------------------------------------------- GEMM (TN, split-K x4)
// part[b,ks] (512x512 bf16) = A[b,ks-chunk]^T @ B[b,ks-chunk]; A,B: (4096x512) row-major.
__global__ __launch_bounds__(256)
void gemm_tn_splitk(const bf16* __restrict__ A, int lda, long sA,
                    const bf16* __restrict__ B, int ldb, long sB,
                    bf16* __restrict__ part)
{
    __shared__ __align__(16) short As[64 * 128];
    __shared__ __align__(16) short Bs[64 * 128];
    int bx, by, bzl;
    xcd_swz(bx, by, bzl);
    const int bz = bzl >> 2, ks = bzl & 3;
    const bf16* Ab = A + (long)bz * sA + (long)ks * 1024 * lda + by * 128;
    const bf16* Bb = B + (long)bz * sB + (long)ks * 1024 * ldb + bx * 128;
    const int t = threadIdx.x, lane = t & 63, wid = t >> 6;
    const int wm = wid >> 1, wn = wid & 1, lg = lane >> 4, lr = lane & 15;

    f32x4 acc[4][4];
#pragma unroll
    for (int m = 0; m < 4; ++m)
#pragma unroll
        for (int n = 0; n < 4; ++n) acc[m][n] = (f32x4){0.f, 0.f, 0.f, 0.f};

    for (int kt = 0; kt < 1024; kt += 64) {
#pragma unroll
        for (int i = 0; i < 4; ++i) {
            const int ch = i * 256 + t;                 // linear 16B-chunk id
            const int row = ch >> 4;                    // k within tile
            const int cs = (ch & 15) ^ (((row >> 3) & 3) << 1);  // swizzled src chunk
            GLL(Ab + (long)(kt + row) * lda + (cs << 3), (char*)As + i * 4096 + wid * 1024);
            GLL(Bb + (long)(kt + row) * ldb + (cs << 3), (char*)Bs + i * 4096 + wid * 1024);
        }
        __syncthreads();
#pragma unroll
        for (int kk = 0; kk < 2; ++kk) {
            bh8 af[4], bfv[4];
#pragma unroll
            for (int m = 0; m < 4; ++m) {
                const int col = wm * 64 + m * 16 + lr;
#pragma unroll
                for (int u = 0; u < 8; ++u) {
                    const int row = kk * 32 + lg * 8 + u;
                    af[m][u] = As[row * 128 + (((col >> 3) ^ (((row >> 3) & 3) << 1)) << 3) + (col & 7)];
                }
            }
#pragma unroll
            for (int n = 0; n < 4; ++n) {
                const int col = wn * 64 + n * 16 + lr;
#pragma unroll
                for (int u = 0; u < 8; ++u) {
                    const int row = kk * 32 + lg * 8 + u;
                    bfv[n][u] = Bs[row * 128 + (((col >> 3) ^ (((row >> 3) & 3) << 1)) << 3) + (col & 7)];
                }
            }
#pragma unroll
            for (int m = 0; m < 4; ++m)
#pragma unroll
                for (int n = 0; n < 4; ++n)
                    acc[m][n] = __builtin_amdgcn_mfma_f32_16x16x32_bf16(af[m], bfv[n], acc[m][n], 0, 0, 0);
        }
        __syncthreads();
    }

    bf16* po = part + ((long)bzl << 18);                // 512*512 per (b,ks)
    const int gr0 = by * 128 + wm * 64;
    const int gc0 = bx * 128 + wn * 64;
#pragma unroll
    for (int m = 0; m < 4; ++m)
#pragma unroll
        for (int n = 0; n < 4; ++n) {
            const int gc = gc0 + n * 16 + lr;
#pragma unroll
            for (int r = 0; r < 4; ++r) {
                const int gr = gr0 + m * 16 + lg * 4 + r;
                po[(long)gr * 512 + gc] = __float2bfloat16(acc[m][n][r]);
            }
        }
}

// kvt[b] = bf16( sum_ks part[b,ks] )   — 8 elems/thread, vectorized.
__global__ __launch_bounds__(256)
void k_kvred(const bf16* __restrict__ part, bf16* __restrict__ kvt)
{
    const long e = ((long)blockIdx.x * 256 + threadIdx.x) * 8;
    const int b = (int)(e >> 18);
    const int off = (int)(e & 262143);
    float s[8] = {0.f, 0.f, 0.f, 0.f, 0.f, 0.f, 0.f, 0.f};
#pragma unroll
    for (int ks = 0; ks < 4; ++ks) {
        bh8 v = *(const bh8*)(part + (((long)(b * 4 + ks)) << 18) + off);
#pragma unroll
        for (int j = 0; j < 8; ++j) s[j] += bf2f(v[j]);
    }
    bh8 o;
#pragma unroll
    for (int j = 0; j < 8; ++j) o[j] = f2bf(s[j]);
    *(bh8*)(kvt + ((long)b << 18) + off) = o;
}

// ---------------------------------------------------------------- transpose
__global__ __launch_bounds__(256)
void k_transpose(const float* __restrict__ src, bf16* __restrict__ dst,
                 int Rd, int Cd, long sSrc, long sDst)
{
    __shared__ float tile[64][65];
    const float* s = src + (long)blockIdx.z * sSrc;
    bf16* d = dst + (long)blockIdx.z * sDst;
    const int r0 = blockIdx.x * 64, c0 = blockIdx.y * 64;
    const int t = threadIdx.x;
#pragma unroll 4
    for (int i = 0; i < 16; ++i) {
        int idx = i * 256 + t;
        int a = idx >> 6, b = idx & 63;
        tile[a][b] = s[(long)(c0 + a) * Rd + r0 + b];
    }
    __syncthreads();
#pragma unroll 4
    for (int i = 0; i < 16; ++i) {
        int idx = i * 256 + t;
        int a = idx >> 6, b = idx & 63;
        d[(long)(r0 + a) * Cd + c0 + b] = __float2bfloat16(tile[b][a]);
    }
}

// convert the three 512x512 conv weights in one pass
__global__ void k_cvt3(const float* __restrict__ a, const float* __restrict__ b,
                       const float* __restrict__ c, bf16* __restrict__ oa,
                       bf16* __restrict__ ob, bf16* __restrict__ oc) {
    int i = blockIdx.x * 256 + threadIdx.x;
    if (i < 262144) {
        oa[i] = __float2bfloat16(a[i]);
        ob[i] = __float2bfloat16(b[i]);
        oc[i] = __float2bfloat16(c[i]);
    }
}

// invsc (512) + dw-weight transpose + combined qkv bias (1536)
__global__ void k_prep(const float* __restrict__ scale, float* __restrict__ invsc,
                       const float* __restrict__ w, float* __restrict__ wT,
                       const float* __restrict__ bq, const float* __restrict__ bk,
                       const float* __restrict__ bv, float* __restrict__ bqkv) {
    int i = blockIdx.x * 256 + threadIdx.x;
    if (i < 512) invsc[i] = 1.0f / log1pf(expf(scale[i]));
    if (i < 1536) bqkv[i] = (i < 512 ? bq[i] : (i < 1024 ? bk[i - 512] : bv[i - 1024]));
    if (i < HIDD * 9) {
        int chn = i / 9, kk = i % 9;
        wT[kk * HIDD + chn] = w[i];
    }
}

__global__ void k_fill(float* o, int n, float v) {
    int i = blockIdx.x * 256 + threadIdx.x; if (i < n) o[i] = v;
}

// ------------------------------------------------- q column-softmax denom
// qe holds bf16 exp(conv_q); column j = stride-CDIM walk of flat buf.
__global__ __launch_bounds__(256)
void k_qcol_partial(const bf16* __restrict__ qe, float* __restrict__ qpart) {
    const int j = blockIdx.x * 256 + threadIdx.x;
    const int ic = blockIdx.y, b = blockIdx.z;     // 16 chunks of 256 rows
    const bf16* p = qe + (long)b * (NDIM * CDIM) + (long)ic * 256 * CDIM + j;
    float s = 0.f;
    for (int i = 0; i < 256; ++i) s += bf2f(*(const short*)(p + (long)i * CDIM));
    qpart[((long)b * 16 + ic) * CDIM + j] = s;
}

// combined second-stage reduce: qsum (idx<4096) and ksum (idx>=4096)
__global__ __launch_bounds__(256)
void k_red2(const float* __restrict__ qpart, float* __restrict__ qsum,
            const float* __restrict__ kpart, float* __restrict__ ksum) {
    const int idx = blockIdx.x * 256 + threadIdx.x;  // 8192
    const int which = idx >> 12, r = idx & 4095;
    const int b = r >> 9, c = r & 511;
    const float* src = which ? kpart : qpart;
    float s = 0.f;
#pragma unroll
    for (int jc = 0; jc < 16; ++jc) s += src[((long)(b * 16 + jc)) * CDIM + c];
    (which ? ksum : qsum)[r] = s;
}

// q row pass + fused z
__global__ __launch_bounds__(256)
void k_qrow(const bf16* __restrict__ qe, const float* __restrict__ qsum,
            const float* __restrict__ invsc, bf16* __restrict__ qb,
            const float* __restrict__ ksum, float* __restrict__ z)
{
    const long row = (long)blockIdx.x * 4 + (threadIdx.x >> 6);
    const int lane = threadIdx.x & 63;
    const int b = (int)(row >> 12);
    bh8 ev = *(const bh8*)(qe + row * CDIM + lane * 8);
    const float* qs = qsum + b * CDIM + lane * 8;
    const float* is = invsc + lane * 8;
    f32x4 s0 = *(const f32x4*)qs, s1 = *(const f32x4*)(qs + 4);
    f32x4 i0 = *(const f32x4*)is, i1 = *(const f32x4*)(is + 4);
    float q[8];
#pragma unroll
    for (int k = 0; k < 4; ++k) {
        q[k]     = (bf2f(ev[k]) / s0[k] + 1e-6f) * i0[k];
        q[k + 4] = (bf2f(ev[k + 4]) / s1[k] + 1e-6f) * i1[k];
    }
    float s2 = 0.f, s6 = 0.f, q3[8];
#pragma unroll
    for (int k = 0; k < 8; ++k) { s2 += q[k] * q[k]; float c = q[k] * q[k] * q[k]; q3[k] = c; s6 += c * c; }
    s2 = wsum(s2); s6 = wsum(s6);
    const float sc = sqrtf(s2) / sqrtf(s6);
    bh8 o;
#pragma unroll
    for (int k = 0; k < 8; ++k) o[k] = f2bf(q3[k] * sc);
    *(bh8*)(qb + row * CDIM + lane * 8) = o;
    // fused z
    const float* ks = ksum + (long)b * CDIM + lane * 8;
    f32x4 k0 = *(const f32x4*)ks, k1 = *(const f32x4*)(ks + 4);
    float zd = 0.f;
#pragma unroll
    for (int j = 0; j < 4; ++j) { zd += bf2f(o[j]) * k0[j]; zd += bf2f(o[j + 4]) * k1[j]; }
    zd = wsum(zd);
    if (lane == 0) z[row] = 1.0f / (zd + 1e-6f);
}

// k row pass (IN-PLACE, bf16): row softmax (axis=2), /sc, cube, renorm.
__global__ __launch_bounds__(256)
void k_krow(bf16* __restrict__ kb, const float* __restrict__ invsc)
{
    const long row = (long)blockIdx.x * 4 + (threadIdx.x >> 6);
    const int lane = threadIdx.x & 63;
    bh8 v = *(const bh8*)(kb + row * CDIM + lane * 8);
    const float* is = invsc + lane * 8;
    f32x4 i0 = *(const f32x4*)is, i1 = *(const f32x4*)(is + 4);
    float xv[8];
#pragma unroll
    for (int k = 0; k < 8; ++k) xv[k] = bf2f(v[k]);
    float mx = -1e30f;
#pragma unroll
    for (int k = 0; k < 8; ++k) mx = fmaxf(mx, xv[k]);
    mx = wmax(mx);
    float e[8], se = 0.f;
#pragma unroll
    for (int k = 0; k < 8; ++k) { e[k] = expf(xv[k] - mx); se += e[k]; }
    se = wsum(se);
    const float inv = 1.0f / se;
    float q[8];
#pragma unroll
    for (int k = 0; k < 4; ++k) {
        q[k]     = (e[k] * inv + 1e-6f) * i0[k];
        q[k + 4] = (e[k + 4] * inv + 1e-6f) * i1[k];
    }
    float s2 = 0.f, s6 = 0.f, q3[8];
#pragma unroll
    for (int k = 0; k < 8; ++k) { s2 += q[k] * q[k]; float c = q[k] * q[k] * q[k]; q3[k] = c; s6 += c * c; }
    s2 = wsum(s2); s6 = wsum(s6);
    const float sc = sqrtf(s2) / sqrtf(s6);
    bh8 o;
#pragma unroll
    for (int k = 0; k < 8; ++k) o[k] = f2bf(q3[k] * sc);
    *(bh8*)(kb + row * CDIM + lane * 8) = o;
}

// ksum partials: column sum of (N,C) rows, 16 chunks of 256 rows.
__global__ __launch_bounds__(256)
void k_colsum_part(const bf16* __restrict__ kb, float* __restrict__ part) {
    const int b = blockIdx.y, jc = blockIdx.x, t = threadIdx.x;
    const bf16* p = kb + (long)b * (NDIM * CDIM) + (long)jc * 256 * CDIM + t * 2;
    float s0 = 0.f, s1 = 0.f;
    for (int j = 0; j < 256; ++j) {
        unsigned u = *(const unsigned*)(p + (long)j * CDIM);
        s0 += bf2f((short)(u & 0xffff));
        s1 += bf2f((short)(u >> 16));
    }
    float* o = part + ((long)b * 16 + jc) * CDIM + t * 2;
    o[0] = s0; o[1] = s1;
}

// LN over 512 (lnm), fp32 in -> bf16 out. 1 wave/row.
__global__ __launch_bounds__(256)
void k_ln512(const float* __restrict__ src, const float* __restrict__ g,
             const float* __restrict__ bta, bf16* __restrict__ dst)
{
    const long row = (long)blockIdx.x * 4 + (threadIdx.x >> 6);
    const int lane = threadIdx.x & 63;
    const float* p = src + row * CDIM + lane * 8;
    f32x4 a0 = *(const f32x4*)p, a1 = *(const f32x4*)(p + 4);
    float s = 0.f, ss = 0.f;
#pragma unroll
    for (int k = 0; k < 4; ++k) { s += a0[k] + a1[k]; ss += a0[k] * a0[k] + a1[k] * a1[k]; }
    s = wsum(s); ss = wsum(ss);
    const float mean = s * (1.0f / 512), var = ss * (1.0f / 512) - mean * mean;
    const float rstd = rsqrtf(var + 1e-5f);
    const float* gp = g + lane * 8;
    const float* bp = bta + lane * 8;
    f32x4 g0 = *(const f32x4*)gp, g1 = *(const f32x4*)(gp + 4);
    f32x4 b0 = *(const f32x4*)bp, b1 = *(const f32x4*)(bp + 4);
    bh8 o;
#pragma unroll
    for (int k = 0; k < 4; ++k) {
        o[k]     = f2bf((a0[k] - mean) * rstd * g0[k] + b0[k]);
        o[k + 4] = f2bf((a1[k] - mean) * rstd * g1[k] + b1[k]);
    }
    *(bh8*)(dst + row * CDIM + lane * 8) = o;
}

// depthwise 3x3 (SAME) + skip + LN(2048) + exact GELU.
__global__ __launch_bounds__(256)
void k_dwlngelu4(const bf16* __restrict__ a, const float* __restrict__ dwwT,
                 const float* __restrict__ dwb, const float* __restrict__ g1,
                 const float* __restrict__ b1, bf16* __restrict__ ax)
{
    const long s0 = (long)blockIdx.x * 4;       // quad-base token (quarter-local)
    const int h = (int)((s0 >> 6) & 63);
    const int w0 = (int)(s0 & 63);
    const int ch = threadIdx.x * 8;

    float wgt[9][8];
#pragma unroll
    for (int kk = 0; kk < 9; ++kk) {
        f32x4 w0v = *(const f32x4*)(dwwT + kk * HIDD + ch);
        f32x4 w1v = *(const f32x4*)(dwwT + kk * HIDD + ch + 4);
#pragma unroll
        for (int j = 0; j < 4; ++j) { wgt[kk][j] = w0v[j]; wgt[kk][j + 4] = w1v[j]; }
    }
#pragma unroll
    for (int j = 0; j < 8; ++j) wgt[4][j] += 1.0f;   // fold the skip (dw + a)

    float acc[4][8];
    {
        f32x4 d0 = *(const f32x4*)(dwb + ch), d1 = *(const f32x4*)(dwb + ch + 4);
#pragma unroll
        for (int ti = 0; ti < 4; ++ti)
#pragma unroll
            for (int j = 0; j < 4; ++j) { acc[ti][j] = d0[j]; acc[ti][j + 4] = d1[j]; }
    }

#pragma unroll
    for (int dy = -1; dy <= 1; ++dy) {
        const int hh = h + dy;
        if ((unsigned)hh >= 64u) continue;       // wave-uniform
#pragma unroll
        for (int c = -1; c <= 4; ++c) {
            const int ww = w0 + c;
            if ((unsigned)ww >= 64u) continue;   // wave-uniform
            bh8 v = *(const bh8*)(a + (s0 + (long)dy * 64 + c) * HIDD + ch);
            float f[8];
#pragma unroll
            for (int j = 0; j < 8; ++j) f[j] = bf2f(v[j]);
#pragma unroll
            for (int ti = 0; ti < 4; ++ti) {
                const int dx = c - ti;
                if (dx < -1 || dx > 1) continue;
                const int kk = (dy + 1) * 3 + (dx + 1);
#pragma unroll
                for (int j = 0; j < 8; ++j) acc[ti][j] += wgt[kk][j] * f[j];
            }
        }
    }

    // LN(2048) per token
    float sv[4], qv[4];
#pragma unroll
    for (int ti = 0; ti < 4; ++ti) {
        float s = 0.f, q = 0.f;
#pragma unroll
        for (int j = 0; j < 8; ++j) { s += acc[ti][j]; q += acc[ti][j] * acc[ti][j]; }
        sv[ti] = wsum(s); qv[ti] = wsum(q);
    }
    __shared__ float red[4][4][2];
    const int wid = threadIdx.x >> 6, lane = threadIdx.x & 63;
    if (lane == 0)
#pragma unroll
        for (int ti = 0; ti < 4; ++ti) { red[wid][ti][0] = sv[ti]; red[wid][ti][1] = qv[ti]; }
    __syncthreads();

    f32x4 ga = *(const f32x4*)(g1 + ch), gb = *(const f32x4*)(g1 + ch + 4);
    f32x4 ba = *(const f32x4*)(b1 + ch), bb = *(const f32x4*)(b1 + ch + 4);
    float gg[8], bb8[8];
#pragma unroll
    for (int j = 0; j < 4; ++j) { gg[j] = ga[j]; gg[j + 4] = gb[j]; bb8[j] = ba[j]; bb8[j + 4] = bb[j]; }

#pragma unroll
    for (int ti = 0; ti < 4; ++ti) {
        const float s = red[0][ti][0] + red[1][ti][0] + red[2][ti][0] + red[3][ti][0];
        const float q = red[0][ti][1] + red[1][ti][1] + red[2][ti][1] + red[3][ti][1];
        const float mean = s * (1.0f / 2048), var = q * (1.0f / 2048) - mean * mean;
        const float rstd = rsqrtf(var + 1e-5f);
        bh8 o;
#pragma unroll
        for (int j = 0; j < 8; ++j) {
            float y = (acc[ti][j] - mean) * rstd * gg[j] + bb8[j];
            o[j] = f2bf(0.5f * y * (1.0f + erff(y * 0.70710678118654752f)));
        }
        *(bh8*)(ax + (s0 + ti) * HIDD + ch) = o;
    }
}

// ---------------------------------------------------------------- launch
extern "C" void kernel_launch(void* const* d_in, const int* in_sizes, int n_in,
                              void* d_out, int out_size, void* d_ws, size_t ws_size,
                              hipStream_t stream) {
    const float* x     = (const float*)d_in[0];
    const float* Wq    = (const float*)d_in[1];
    const float* bq    = (const float*)d_in[2];
    const float* Wk    = (const float*)d_in[3];
    const float* bk    = (const float*)d_in[4];
    const float* Wv    = (const float*)d_in[5];
    const float* bv    = (const float*)d_in[6];
    const float* scale = (const float*)d_in[7];
    const float* fc1_w = (const float*)d_in[8];
    const float* fc1_b = (const float*)d_in[9];
    const float* dw_w  = (const float*)d_in[10];
    const float* dw_b  = (const float*)d_in[11];
    const float* fc2_w = (const float*)d_in[12];
    const float* fc2_b = (const float*)d_in[13];
    const float* ln1_g = (const float*)d_in[14];
    const float* ln1_b = (const float*)d_in[15];
    const float* lnm_g = (const float*)d_in[16];
    const float* lnm_b = (const float*)d_in[17];
    float* out = (float*)d_out;
    char* p = (char*)d_ws;

    // ---- workspace layout ----
    bf16*  xbT   = (bf16*)(p + 0);            // 32 MiB, alive through EP_ATTN
    bf16*  kb    = (bf16*)(p + 33554432);     // conv-k -> qb -> axbuf
    bf16*  vb    = (bf16*)(p + 67108864);     // conv-v -> tbuf
    bf16*  kvt   = (bf16*)(p + 100663296);    //  4 MiB
    bf16*  wqb   = (bf16*)(p + 104857600);    // wqb|wkb|wvb contiguous = 1536x512
    bf16*  wkb   = (bf16*)(p + 105381888);
    bf16*  wvb   = (bf16*)(p + 105906176);
    bf16*  fc1wT = (bf16*)(p + 106430464);    //  2 MiB
    bf16*  fc2wT = (bf16*)(p + 108527616);    //  2 MiB
    float* invsc = (float*)(p + 110624768);
    float* dwwT  = (float*)(p + 110626816);   // 73,728 B
    float* bqkv  = (float*)(p + 110700544);   //  6,144 B (slack before qsum)
    float* qsum  = (float*)(p + 110757888);
    float* ksum  = (float*)(p + 110905344);
    float* zbuf  = (float*)(p + 110921728);
    const size_t REQUIRED = 111052800;
    float* qpart = (float*)kvt;               // overlays kvt (dead until kvred)
    float* kpart = (float*)((char*)kvt + 262144);
    bf16*  qe    = (bf16*)out;                        // 32 MiB in d_out
    bf16*  kvpart= (bf16*)((char*)out + 33554432);    // 16 MiB bf16 partials
    bf16*  qb    = kb;                        // after splitk, kb dead
    bf16*  abuf  = (bf16*)(p + 0);            // xbT dead after attn
    bf16*  axbuf = (bf16*)(p + 33554432);     // qb dead after attn
    bf16*  tbuf  = (bf16*)(p + 67108864);     // vb dead after splitk

    if (ws_size < REQUIRED) {   // sentinel encodes actual ws size in MiB
        k_fill<<<(out_size + 255) / 256, 256, 0, stream>>>(out, out_size, 100000.0f + (float)(ws_size >> 20));
        return;
    }

    const long NC = (long)NDIM * CDIM;  // 2,097,152 elements per batch

    // pack / convert params
    k_cvt3<<<1024, 256, 0, stream>>>(Wq, Wk, Wv, wqb, wkb, wvb);
    k_transpose<<<dim3(32, 8, 1), 256, 0, stream>>>(fc1_w, fc1wT, 2048, 512, 0, 0);
    k_transpose<<<dim3(8, 32, 1), 256, 0, stream>>>(fc2_w, fc2wT, 512, 2048, 0, 0);
    k_prep<<<72, 256, 0, stream>>>(scale, invsc, dw_w, dwwT, bq, bk, bv, bqkv);
    k_transpose<<<dim3(64, 8, BATCH), 256, 0, stream>>>(x, xbT, 4096, 512, NC, NC);

    // fused conv q/k/v: one GEMM, A = [Wq;Wk;Wv] (1536x512), B staged once
    gemm_bt<EP_QKV, 128><<<dim3(32, 12, 8), 256, 0, stream>>>(
        wqb, 512, 0, xbT, 512, NC, qe, 4096, NC, 512, bqkv, kb, 0, vb, 0);

    // softmax denominators (both column chains), then combined reduce
    k_qcol_partial<<<dim3(2, 16, 8), 256, 0, stream>>>(qe, qpart);
    k_krow<<<8192, 256, 0, stream>>>(kb, invsc);
    k_colsum_part<<<dim3(16, 8), 256, 0, stream>>>(kb, kpart);
    k_red2<<<32, 256, 0, stream>>>(qpart, qsum, kpart, ksum);

    // kv^T — split-K x4, bf16 partials in out[32M:48M] (qe untouched)
    gemm_tn_splitk<<<dim3(4, 4, 32), 256, 0, stream>>>(vb, 512, NC, kb, 512, NC, kvpart);
    k_kvred<<<1024, 256, 0, stream>>>(kvpart, kvt);

    // q chain (after splitk so qb can overlay kb) + fused z
    k_qrow<<<8192, 256, 0, stream>>>(qe, qsum, invsc, qb, ksum, zbuf);

    // enhanced = bf16(shortcut from xbT) + z*(q@kv)  -> overwrites all of `out`
    gemm_bt<EP_ATTN, 128><<<dim3(4, 32, 8), 256, 0, stream>>>(qb, 512, NC, kvt, 512, 262144, out, 512, NC, 512, nullptr, xbT, NC, zbuf, 4096);

    // MixFFN: LN once over all rows, then 4 quarters over dead buffers
    k_ln512<<<8192, 256, 0, stream>>>(out, lnm_g, lnm_b, tbuf);
    for (int q4 = 0; q4 < 4; ++q4) {
        float* outq = out + (long)q4 * 8192 * CDIM;
        bf16* tq = tbuf + (long)q4 * 8192 * CDIM;
        gemm_bt<EP_BF16_BCOL, 128><<<dim3(16, 64, 1), 256, 0, stream>>>(tq, 512, 0, fc1wT, 512, 0, abuf, 2048, 0, 512, fc1_b, nullptr, 0, nullptr, 0);
        k_dwlngelu4<<<2048, 256, 0, stream>>>(abuf, dwwT, dw_b, ln1_g, ln1_b, axbuf);
        gemm_bt<EP_OUT, 64><<<dim3(4, 128, 1), 256, 0, stream>>>(axbuf, 2048, 0, fc2wT, 2048, 0, outq, 512, 0, 2048, fc2_b, outq, 0, nullptr, 0);
    }
}

// Round 9
// 631.896 us; speedup vs baseline: 1.0195x; 1.0195x over previous
//
#include <hip/hip_runtime.h>
#include <hip/hip_bf16.h>

typedef __hip_bfloat16 bf16;
typedef __attribute__((ext_vector_type(8))) short bh8;      // 8 x bf16 bits
typedef __attribute__((ext_vector_type(4))) short bh4;      // 4 x bf16 bits
typedef __attribute__((ext_vector_type(4))) float f32x4;

#define CDIM 512
#define NDIM 4096
#define HIDD 2048
#define BATCH 8

__device__ __forceinline__ float bf2f(short s) {
    union { unsigned u; float f; } c; c.u = ((unsigned)(unsigned short)s) << 16; return c.f;
}
__device__ __forceinline__ short f2bf(float f) {
    union { __hip_bfloat16 h; short s; } c; c.h = __float2bfloat16(f); return c.s;
}
__device__ __forceinline__ float wsum(float v) {
#pragma unroll
    for (int o = 32; o; o >>= 1) v += __shfl_xor(v, o);
    return v;
}
__device__ __forceinline__ float wmax(float v) {
#pragma unroll
    for (int o = 32; o; o >>= 1) v = fmaxf(v, __shfl_xor(v, o));
    return v;
}

#define GLL(g, l) __builtin_amdgcn_global_load_lds( \
    (const __attribute__((address_space(1))) unsigned int*)(g), \
    (__attribute__((address_space(3))) unsigned int*)(l), 16, 0, 0)

// ---------------------------------------------------------------- GEMM (NT)
// C[M,N] = A(M,K) @ Bt(N,K)^T, row-major bf16, fp32 accum. TMx128 tile, BK=64.
// LDS tiles XOR-swizzled (pre-swizzled GLL source + swizzled fragment read).
// MFAST=1: decompose block id M-tile-fastest (B-panel reuse back-to-back).
enum { EP_QEXP = 0, EP_BF16_BROW = 1, EP_ATTN = 3, EP_BF16_BCOL = 4, EP_OUT = 5, EP_QKV = 6 };

template<int MODE, int TM, int MFAST>
__global__ __launch_bounds__(256)
void gemm_bt(const bf16* __restrict__ A, int lda, long sA,
             const bf16* __restrict__ Bt, int ldb, long sB,
             void* __restrict__ Cp, int ldc, long sC, int K,
             const float* __restrict__ bias,
             const void* __restrict__ aux1, long sAux1,
             const void* __restrict__ aux2, long sAux2)
{
    constexpr int MF = TM / 32;                 // A-frags per wave; also A-chunks/thread
    __shared__ __align__(16) bf16 As[TM * 64];
    __shared__ __align__(16) bf16 Bs[128 * 64];
    int bx, by, bz;
    {
        const int gx = gridDim.x, gy = gridDim.y;
        const int nwg = gx * gy * gridDim.z;
        int lid = blockIdx.x + gx * (blockIdx.y + gy * blockIdx.z);
        const int cpx = nwg >> 3;
        int swz = (lid & 7) * cpx + (lid >> 3);
        if constexpr (MFAST) {
            by = swz % gy; swz /= gy;           // M-tile fastest: B-panel reuse
            bx = swz % gx;
            bz = swz / gx;
        } else {
            bx = swz % gx; swz /= gx;
            by = swz % gy;
            bz = swz / gy;
        }
    }
    const bf16* Ab = A + (long)bz * sA + (long)by * TM * lda;
    const bf16* Bb = Bt + (long)bz * sB + (long)bx * 128 * ldb;
    const int t = threadIdx.x, lane = t & 63, wid = t >> 6;
    const int wm = wid >> 1, wn = wid & 1, lg = lane >> 4, lr = lane & 15;

    f32x4 acc[MF][4];
#pragma unroll
    for (int m = 0; m < MF; ++m)
#pragma unroll
        for (int n = 0; n < 4; ++n) acc[m][n] = (f32x4){0.f, 0.f, 0.f, 0.f};

    for (int kt = 0; kt < K; kt += 64) {
#pragma unroll
        for (int i = 0; i < MF; ++i) {
            const int ch = i * 256 + t;
            const int row = ch >> 3;
            const int cs = (ch & 7) ^ (row & 7);    // pre-swizzled source chunk
            GLL(Ab + (long)row * lda + kt + (cs << 3), (char*)As + i * 4096 + wid * 1024);
        }
#pragma unroll
        for (int i = 0; i < 4; ++i) {
            const int ch = i * 256 + t;
            const int row = ch >> 3;
            const int cs = (ch & 7) ^ (row & 7);
            GLL(Bb + (long)row * ldb + kt + (cs << 3), (char*)Bs + i * 4096 + wid * 1024);
        }
        __syncthreads();
#pragma unroll
        for (int kk = 0; kk < 2; ++kk) {
            bh8 af[MF], bfv[4];
#pragma unroll
            for (int m = 0; m < MF; ++m) {
                const int row = wm * (TM / 2) + m * 16 + lr;
                const int kc = (kk * 4 + lg) ^ (row & 7);
                af[m] = *(const bh8*)(As + row * 64 + kc * 8);
            }
#pragma unroll
            for (int n = 0; n < 4; ++n) {
                const int row = wn * 64 + n * 16 + lr;
                const int kc = (kk * 4 + lg) ^ (row & 7);
                bfv[n] = *(const bh8*)(Bs + row * 64 + kc * 8);
            }
#pragma unroll
            for (int m = 0; m < MF; ++m)
#pragma unroll
                for (int n = 0; n < 4; ++n)
                    acc[m][n] = __builtin_amdgcn_mfma_f32_16x16x32_bf16(af[m], bfv[n], acc[m][n], 0, 0, 0);
        }
        __syncthreads();
    }

    const int gr0 = by * TM + wm * (TM / 2);
    const int gc0 = bx * 128 + wn * 64;
#pragma unroll
    for (int m = 0; m < MF; ++m) {
#pragma unroll
        for (int n = 0; n < 4; ++n) {
            const int gc = gc0 + n * 16 + lr;
#pragma unroll
            for (int r = 0; r < 4; ++r) {
                const int gr = gr0 + m * 16 + lg * 4 + r;
                float v = acc[m][n][r];
                if constexpr (MODE == EP_QKV) {
                    // fused conv q/k/v: rows 0-511 -> qe (exp), 512-1023 -> kb, 1024-1535 -> vb
                    const int which = gr >> 9, grl = gr & 511;   // wave-uniform per block
                    const float vb_ = v + bias[gr];
                    if (which == 0)
                        ((bf16*)Cp + (long)bz * sC)[(long)grl * ldc + gc] = __float2bfloat16(expf(vb_));
                    else if (which == 1)
                        ((bf16*)aux1 + (long)bz * sC)[(long)grl * ldc + gc] = __float2bfloat16(vb_);
                    else
                        ((bf16*)aux2 + (long)bz * sC)[(long)grl * ldc + gc] = __float2bfloat16(vb_);
                } else if constexpr (MODE == EP_QEXP) {
                    ((bf16*)Cp + (long)bz * sC)[(long)gr * ldc + gc] = __float2bfloat16(expf(v + bias[gr]));
                } else if constexpr (MODE == EP_BF16_BROW) {
                    ((bf16*)Cp + (long)bz * sC)[(long)gr * ldc + gc] = __float2bfloat16(v + bias[gr]);
                } else if constexpr (MODE == EP_ATTN) {
                    // shortcut from xbT (bf16, (N,C) row-major -> coalesced)
                    const bf16* xg = (const bf16*)aux1 + (long)bz * sAux1;
                    const float* zg = (const float*)aux2 + (long)bz * sAux2;   // z[b] (N)
                    ((float*)Cp + (long)bz * sC)[(long)gr * ldc + gc] =
                        zg[gr] * v + bf2f(*(const short*)(xg + (long)gr * 512 + gc));
                } else if constexpr (MODE == EP_BF16_BCOL) {
                    ((bf16*)Cp + (long)bz * sC)[(long)gr * ldc + gc] = __float2bfloat16(v + bias[gc]);
                } else { // EP_OUT: out = acc + bias[col] + out (in-place residual)
                    float* op = (float*)Cp;
                    const long idx = (long)gr * ldc + gc;
                    op[idx] = v + bias[gc] + ((const float*)aux1)[idx];
                }
            }
        }
    }
}

// ---------------------------------------------------------------- GEMM (TN, split-K x4)
// part[b,ks] (512x512 bf16) = A[b,ks-chunk]^T @ B[b,ks-chunk]; A,B: (4096x512) row-major.
__global__ __launch_bounds__(256)
void gemm_tn_splitk(const bf16* __restrict__ A, int lda, long sA,
                    const bf16* __restrict__ B, int ldb, long sB,
                    bf16* __restrict__ part)
{
    __shared__ __align__(16) short As[64 * 128];
    __shared__ __align__(16) short Bs[64 * 128];
    int bx, by, bzl;
    {
        const int gx = gridDim.x, gy = gridDim.y;
        const int nwg = gx * gy * gridDim.z;
        int lid = blockIdx.x + gx * (blockIdx.y + gy * blockIdx.z);
        const int cpx = nwg >> 3;
        int swz = (lid & 7) * cpx + (lid >> 3);
        bx = swz % gx; swz /= gx;
        by = swz % gy;
        bzl = swz / gy;
    }
    const int bz = bzl >> 2, ks = bzl & 3;
    const bf16* Ab = A + (long)bz * sA + (long)ks * 1024 * lda + by * 128;
    const bf16* Bb = B + (long)bz * sB + (long)ks * 1024 * ldb + bx * 128;
    const int t = threadIdx.x, lane = t & 63, wid = t >> 6;
    const int wm = wid >> 1, wn = wid & 1, lg = lane >> 4, lr = lane & 15;

    f32x4 acc[4][4];
#pragma unroll
    for (int m = 0; m < 4; ++m)
#pragma unroll
        for (int n = 0; n < 4; ++n) acc[m][n] = (f32x4){0.f, 0.f, 0.f, 0.f};

    for (int kt = 0; kt < 1024; kt += 64) {
#pragma unroll
        for (int i = 0; i < 4; ++i) {
            const int ch = i * 256 + t;                 // linear 16B-chunk id
            const int row = ch >> 4;                    // k within tile
            const int cs = (ch & 15) ^ (((row >> 3) & 3) << 1);  // swizzled src chunk
            GLL(Ab + (long)(kt + row) * lda + (cs << 3), (char*)As + i * 4096 + wid * 1024);
            GLL(Bb + (long)(kt + row) * ldb + (cs << 3), (char*)Bs + i * 4096 + wid * 1024);
        }
        __syncthreads();
#pragma unroll
        for (int kk = 0; kk < 2; ++kk) {
            bh8 af[4], bfv[4];
#pragma unroll
            for (int m = 0; m < 4; ++m) {
                const int col = wm * 64 + m * 16 + lr;
#pragma unroll
                for (int u = 0; u < 8; ++u) {
                    const int row = kk * 32 + lg * 8 + u;
                    af[m][u] = As[row * 128 + (((col >> 3) ^ (((row >> 3) & 3) << 1)) << 3) + (col & 7)];
                }
            }
#pragma unroll
            for (int n = 0; n < 4; ++n) {
                const int col = wn * 64 + n * 16 + lr;
#pragma unroll
                for (int u = 0; u < 8; ++u) {
                    const int row = kk * 32 + lg * 8 + u;
                    bfv[n][u] = Bs[row * 128 + (((col >> 3) ^ (((row >> 3) & 3) << 1)) << 3) + (col & 7)];
                }
            }
#pragma unroll
            for (int m = 0; m < 4; ++m)
#pragma unroll
                for (int n = 0; n < 4; ++n)
                    acc[m][n] = __builtin_amdgcn_mfma_f32_16x16x32_bf16(af[m], bfv[n], acc[m][n], 0, 0, 0);
        }
        __syncthreads();
    }

    bf16* po = part + ((long)bzl << 18);                // 512*512 per (b,ks)
    const int gr0 = by * 128 + wm * 64;
    const int gc0 = bx * 128 + wn * 64;
#pragma unroll
    for (int m = 0; m < 4; ++m)
#pragma unroll
        for (int n = 0; n < 4; ++n) {
            const int gc = gc0 + n * 16 + lr;
#pragma unroll
            for (int r = 0; r < 4; ++r) {
                const int gr = gr0 + m * 16 + lg * 4 + r;
                po[(long)gr * 512 + gc] = __float2bfloat16(acc[m][n][r]);
            }
        }
}

// kvt[b] = bf16( sum_ks part[b,ks] )   — 8 elems/thread, vectorized.
__global__ __launch_bounds__(256)
void k_kvred(const bf16* __restrict__ part, bf16* __restrict__ kvt)
{
    const long e = ((long)blockIdx.x * 256 + threadIdx.x) * 8;
    const int b = (int)(e >> 18);
    const int off = (int)(e & 262143);
    float s[8] = {0.f, 0.f, 0.f, 0.f, 0.f, 0.f, 0.f, 0.f};
#pragma unroll
    for (int ks = 0; ks < 4; ++ks) {
        bh8 v = *(const bh8*)(part + (((long)(b * 4 + ks)) << 18) + off);
#pragma unroll
        for (int j = 0; j < 8; ++j) s[j] += bf2f(v[j]);
    }
    bh8 o;
#pragma unroll
    for (int j = 0; j < 8; ++j) o[j] = f2bf(s[j]);
    *(bh8*)(kvt + ((long)b << 18) + off) = o;
}

// ---------------------------------------------------------------- transpose
__global__ __launch_bounds__(256)
void k_transpose(const float* __restrict__ src, bf16* __restrict__ dst,
                 int Rd, int Cd, long sSrc, long sDst)
{
    __shared__ float tile[64][65];
    const float* s = src + (long)blockIdx.z * sSrc;
    bf16* d = dst + (long)blockIdx.z * sDst;
    const int r0 = blockIdx.x * 64, c0 = blockIdx.y * 64;
    const int t = threadIdx.x;
#pragma unroll 4
    for (int i = 0; i < 16; ++i) {
        int idx = i * 256 + t;
        int a = idx >> 6, b = idx & 63;
        tile[a][b] = s[(long)(c0 + a) * Rd + r0 + b];
    }
    __syncthreads();
#pragma unroll 4
    for (int i = 0; i < 16; ++i) {
        int idx = i * 256 + t;
        int a = idx >> 6, b = idx & 63;
        d[(long)(r0 + a) * Cd + c0 + b] = __float2bfloat16(tile[b][a]);
    }
}

// one-shot setup: conv-weight cvt (3x), invsc, qkv bias, dw-weight transpose
__global__ void k_setup(const float* __restrict__ Wq, const float* __restrict__ Wk,
                        const float* __restrict__ Wv, bf16* __restrict__ oq,
                        bf16* __restrict__ ok, bf16* __restrict__ ov,
                        const float* __restrict__ scale, float* __restrict__ invsc,
                        const float* __restrict__ w, float* __restrict__ wT,
                        const float* __restrict__ bq, const float* __restrict__ bk,
                        const float* __restrict__ bv, float* __restrict__ bqkv) {
    int i = blockIdx.x * 256 + threadIdx.x;
    if (i < 262144) {
        oq[i] = __float2bfloat16(Wq[i]);
        ok[i] = __float2bfloat16(Wk[i]);
        ov[i] = __float2bfloat16(Wv[i]);
    }
    if (i < 512) invsc[i] = 1.0f / log1pf(expf(scale[i]));
    if (i < 1536) bqkv[i] = (i < 512 ? bq[i] : (i < 1024 ? bk[i - 512] : bv[i - 1024]));
    if (i < HIDD * 9) {
        int chn = i / 9, kk = i % 9;
        wT[kk * HIDD + chn] = w[i];
    }
}

__global__ void k_fill(float* o, int n, float v) {
    int i = blockIdx.x * 256 + threadIdx.x; if (i < n) o[i] = v;
}

// ------------------------------------------------- combined column partial sums
// x<2: qe columns; x>=2: kb columns. Each thread sums 256 rows of one column.
__global__ __launch_bounds__(256)
void k_colsums(const bf16* __restrict__ qe, const bf16* __restrict__ kb,
               float* __restrict__ qpart, float* __restrict__ kpart) {
    const int xb = blockIdx.x;                     // 0..3
    const int ic = blockIdx.y, b = blockIdx.z;     // 16 chunks of 256 rows
    const int j = (xb & 1) * 256 + threadIdx.x;
    const bf16* src = (xb < 2) ? qe : kb;
    const bf16* p = src + (long)b * (NDIM * CDIM) + (long)ic * 256 * CDIM + j;
    float s = 0.f;
    for (int i = 0; i < 256; ++i) s += bf2f(*(const short*)(p + (long)i * CDIM));
    ((xb < 2) ? qpart : kpart)[((long)b * 16 + ic) * CDIM + j] = s;
}

// combined second-stage reduce: qsum (idx<4096) and ksum (idx>=4096)
__global__ __launch_bounds__(256)
void k_red2(const float* __restrict__ qpart, float* __restrict__ qsum,
            const float* __restrict__ kpart, float* __restrict__ ksum) {
    const int idx = blockIdx.x * 256 + threadIdx.x;  // 8192
    const int which = idx >> 12, r = idx & 4095;
    const int b = r >> 9, c = r & 511;
    const float* src = which ? kpart : qpart;
    float s = 0.f;
#pragma unroll
    for (int jc = 0; jc < 16; ++jc) s += src[((long)(b * 16 + jc)) * CDIM + c];
    (which ? ksum : qsum)[r] = s;
}

// q row pass + fused z
__global__ __launch_bounds__(256)
void k_qrow(const bf16* __restrict__ qe, const float* __restrict__ qsum,
            const float* __restrict__ invsc, bf16* __restrict__ qb,
            const float* __restrict__ ksum, float* __restrict__ z)
{
    const long row = (long)blockIdx.x * 4 + (threadIdx.x >> 6);
    const int lane = threadIdx.x & 63;
    const int b = (int)(row >> 12);
    bh8 ev = *(const bh8*)(qe + row * CDIM + lane * 8);
    const float* qs = qsum + b * CDIM + lane * 8;
    const float* is = invsc + lane * 8;
    f32x4 s0 = *(const f32x4*)qs, s1 = *(const f32x4*)(qs + 4);
    f32x4 i0 = *(const f32x4*)is, i1 = *(const f32x4*)(is + 4);
    float q[8];
#pragma unroll
    for (int k = 0; k < 4; ++k) {
        q[k]     = (bf2f(ev[k]) / s0[k] + 1e-6f) * i0[k];
        q[k + 4] = (bf2f(ev[k + 4]) / s1[k] + 1e-6f) * i1[k];
    }
    float s2 = 0.f, s6 = 0.f, q3[8];
#pragma unroll
    for (int k = 0; k < 8; ++k) { s2 += q[k] * q[k]; float c = q[k] * q[k] * q[k]; q3[k] = c; s6 += c * c; }
    s2 = wsum(s2); s6 = wsum(s6);
    const float sc = sqrtf(s2) / sqrtf(s6);
    bh8 o;
#pragma unroll
    for (int k = 0; k < 8; ++k) o[k] = f2bf(q3[k] * sc);
    *(bh8*)(qb + row * CDIM + lane * 8) = o;
    // fused z
    const float* ks = ksum + (long)b * CDIM + lane * 8;
    f32x4 k0 = *(const f32x4*)ks, k1 = *(const f32x4*)(ks + 4);
    float zd = 0.f;
#pragma unroll
    for (int j = 0; j < 4; ++j) { zd += bf2f(o[j]) * k0[j]; zd += bf2f(o[j + 4]) * k1[j]; }
    zd = wsum(zd);
    if (lane == 0) z[row] = 1.0f / (zd + 1e-6f);
}

// k row pass (IN-PLACE, bf16): row softmax (axis=2), /sc, cube, renorm.
__global__ __launch_bounds__(256)
void k_krow(bf16* __restrict__ kb, const float* __restrict__ invsc)
{
    const long row = (long)blockIdx.x * 4 + (threadIdx.x >> 6);
    const int lane = threadIdx.x & 63;
    bh8 v = *(const bh8*)(kb + row * CDIM + lane * 8);
    const float* is = invsc + lane * 8;
    f32x4 i0 = *(const f32x4*)is, i1 = *(const f32x4*)(is + 4);
    float xv[8];
#pragma unroll
    for (int k = 0; k < 8; ++k) xv[k] = bf2f(v[k]);
    float mx = -1e30f;
#pragma unroll
    for (int k = 0; k < 8; ++k) mx = fmaxf(mx, xv[k]);
    mx = wmax(mx);
    float e[8], se = 0.f;
#pragma unroll
    for (int k = 0; k < 8; ++k) { e[k] = expf(xv[k] - mx); se += e[k]; }
    se = wsum(se);
    const float inv = 1.0f / se;
    float q[8];
#pragma unroll
    for (int k = 0; k < 4; ++k) {
        q[k]     = (e[k] * inv + 1e-6f) * i0[k];
        q[k + 4] = (e[k + 4] * inv + 1e-6f) * i1[k];
    }
    float s2 = 0.f, s6 = 0.f, q3[8];
#pragma unroll
    for (int k = 0; k < 8; ++k) { s2 += q[k] * q[k]; float c = q[k] * q[k] * q[k]; q3[k] = c; s6 += c * c; }
    s2 = wsum(s2); s6 = wsum(s6);
    const float sc = sqrtf(s2) / sqrtf(s6);
    bh8 o;
#pragma unroll
    for (int k = 0; k < 8; ++k) o[k] = f2bf(q3[k] * sc);
    *(bh8*)(kb + row * CDIM + lane * 8) = o;
}

// LN over 512 (lnm), fp32 in -> bf16 out. 1 wave/row.
__global__ __launch_bounds__(256)
void k_ln512(const float* __restrict__ src, const float* __restrict__ g,
             const float* __restrict__ bta, bf16* __restrict__ dst)
{
    const long row = (long)blockIdx.x * 4 + (threadIdx.x >> 6);
    const int lane = threadIdx.x & 63;
    const float* p = src + row * CDIM + lane * 8;
    f32x4 a0 = *(const f32x4*)p, a1 = *(const f32x4*)(p + 4);
    float s = 0.f, ss = 0.f;
#pragma unroll
    for (int k = 0; k < 4; ++k) { s += a0[k] + a1[k]; ss += a0[k] * a0[k] + a1[k] * a1[k]; }
    s = wsum(s); ss = wsum(ss);
    const float mean = s * (1.0f / 512), var = ss * (1.0f / 512) - mean * mean;
    const float rstd = rsqrtf(var + 1e-5f);
    const float* gp = g + lane * 8;
    const float* bp = bta + lane * 8;
    f32x4 g0 = *(const f32x4*)gp, g1 = *(const f32x4*)(gp + 4);
    f32x4 b0 = *(const f32x4*)bp, b1 = *(const f32x4*)(bp + 4);
    bh8 o;
#pragma unroll
    for (int k = 0; k < 4; ++k) {
        o[k]     = f2bf((a0[k] - mean) * rstd * g0[k] + b0[k]);
        o[k + 4] = f2bf((a1[k] - mean) * rstd * g1[k] + b1[k]);
    }
    *(bh8*)(dst + row * CDIM + lane * 8) = o;
}

// depthwise 3x3 (SAME) + skip + LN(2048) + exact GELU.
__global__ __launch_bounds__(256)
void k_dwlngelu4(const bf16* __restrict__ a, const float* __restrict__ dwwT,
                 const float* __restrict__ dwb, const float* __restrict__ g1,
                 const float* __restrict__ b1, bf16* __restrict__ ax)
{
    const long s0 = (long)blockIdx.x * 4;       // quad-base token (quarter-local)
    const int h = (int)((s0 >> 6) & 63);
    const int w0 = (int)(s0 & 63);
    const int ch = threadIdx.x * 8;

    float wgt[9][8];
#pragma unroll
    for (int kk = 0; kk < 9; ++kk) {
        f32x4 w0v = *(const f32x4*)(dwwT + kk * HIDD + ch);
        f32x4 w1v = *(const f32x4*)(dwwT + kk * HIDD + ch + 4);
#pragma unroll
        for (int j = 0; j < 4; ++j) { wgt[kk][j] = w0v[j]; wgt[kk][j + 4] = w1v[j]; }
    }
#pragma unroll
    for (int j = 0; j < 8; ++j) wgt[4][j] += 1.0f;   // fold the skip (dw + a)

    float acc[4][8];
    {
        f32x4 d0 = *(const f32x4*)(dwb + ch), d1 = *(const f32x4*)(dwb + ch + 4);
#pragma unroll
        for (int ti = 0; ti < 4; ++ti)
#pragma unroll
            for (int j = 0; j < 4; ++j) { acc[ti][j] = d0[j]; acc[ti][j + 4] = d1[j]; }
    }

#pragma unroll
    for (int dy = -1; dy <= 1; ++dy) {
        const int hh = h + dy;
        if ((unsigned)hh >= 64u) continue;       // wave-uniform
#pragma unroll
        for (int c = -1; c <= 4; ++c) {
            const int ww = w0 + c;
            if ((unsigned)ww >= 64u) continue;   // wave-uniform
            bh8 v = *(const bh8*)(a + (s0 + (long)dy * 64 + c) * HIDD + ch);
            float f[8];
#pragma unroll
            for (int j = 0; j < 8; ++j) f[j] = bf2f(v[j]);
#pragma unroll
            for (int ti = 0; ti < 4; ++ti) {
                const int dx = c - ti;
                if (dx < -1 || dx > 1) continue;
                const int kk = (dy + 1) * 3 + (dx + 1);
#pragma unroll
                for (int j = 0; j < 8; ++j) acc[ti][j] += wgt[kk][j] * f[j];
            }
        }
    }

    // LN(2048) per token
    float sv[4], qv[4];
#pragma unroll
    for (int ti = 0; ti < 4; ++ti) {
        float s = 0.f, q = 0.f;
#pragma unroll
        for (int j = 0; j < 8; ++j) { s += acc[ti][j]; q += acc[ti][j] * acc[ti][j]; }
        sv[ti] = wsum(s); qv[ti] = wsum(q);
    }
    __shared__ float red[4][4][2];
    const int wid = threadIdx.x >> 6, lane = threadIdx.x & 63;
    if (lane == 0)
#pragma unroll
        for (int ti = 0; ti < 4; ++ti) { red[wid][ti][0] = sv[ti]; red[wid][ti][1] = qv[ti]; }
    __syncthreads();

    f32x4 ga = *(const f32x4*)(g1 + ch), gb = *(const f32x4*)(g1 + ch + 4);
    f32x4 ba = *(const f32x4*)(b1 + ch), bb = *(const f32x4*)(b1 + ch + 4);
    float gg[8], bb8[8];
#pragma unroll
    for (int j = 0; j < 4; ++j) { gg[j] = ga[j]; gg[j + 4] = gb[j]; bb8[j] = ba[j]; bb8[j + 4] = bb[j]; }

#pragma unroll
    for (int ti = 0; ti < 4; ++ti) {
        const float s = red[0][ti][0] + red[1][ti][0] + red[2][ti][0] + red[3][ti][0];
        const float q = red[0][ti][1] + red[1][ti][1] + red[2][ti][1] + red[3][ti][1];
        const float mean = s * (1.0f / 2048), var = q * (1.0f / 2048) - mean * mean;
        const float rstd = rsqrtf(var + 1e-5f);
        bh8 o;
#pragma unroll
        for (int j = 0; j < 8; ++j) {
            float y = (acc[ti][j] - mean) * rstd * gg[j] + bb8[j];
            o[j] = f2bf(0.5f * y * (1.0f + erff(y * 0.70710678118654752f)));
        }
        *(bh8*)(ax + (s0 + ti) * HIDD + ch) = o;
    }
}

// ---------------------------------------------------------------- launch
extern "C" void kernel_launch(void* const* d_in, const int* in_sizes, int n_in,
                              void* d_out, int out_size, void* d_ws, size_t ws_size,
                              hipStream_t stream) {
    const float* x     = (const float*)d_in[0];
    const float* Wq    = (const float*)d_in[1];
    const float* bq    = (const float*)d_in[2];
    const float* Wk    = (const float*)d_in[3];
    const float* bk    = (const float*)d_in[4];
    const float* Wv    = (const float*)d_in[5];
    const float* bv    = (const float*)d_in[6];
    const float* scale = (const float*)d_in[7];
    const float* fc1_w = (const float*)d_in[8];
    const float* fc1_b = (const float*)d_in[9];
    const float* dw_w  = (const float*)d_in[10];
    const float* dw_b  = (const float*)d_in[11];
    const float* fc2_w = (const float*)d_in[12];
    const float* fc2_b = (const float*)d_in[13];
    const float* ln1_g = (const float*)d_in[14];
    const float* ln1_b = (const float*)d_in[15];
    const float* lnm_g = (const float*)d_in[16];
    const float* lnm_b = (const float*)d_in[17];
    float* out = (float*)d_out;
    char* p = (char*)d_ws;

    // ---- workspace layout ----
    bf16*  xbT   = (bf16*)(p + 0);            // 32 MiB, alive through EP_ATTN
    bf16*  kb    = (bf16*)(p + 33554432);     // conv-k -> qb -> axbuf
    bf16*  vb    = (bf16*)(p + 67108864);     // conv-v -> tbuf
    bf16*  kvt   = (bf16*)(p + 100663296);    //  4 MiB
    bf16*  wqb   = (bf16*)(p + 104857600);    // wqb|wkb|wvb contiguous = 1536x512
    bf16*  wkb   = (bf16*)(p + 105381888);
    bf16*  wvb   = (bf16*)(p + 105906176);
    bf16*  fc1wT = (bf16*)(p + 106430464);    //  2 MiB
    bf16*  fc2wT = (bf16*)(p + 108527616);    //  2 MiB
    float* invsc = (float*)(p + 110624768);
    float* dwwT  = (float*)(p + 110626816);   // 73,728 B
    float* bqkv  = (float*)(p + 110700544);   //  6,144 B
    float* qsum  = (float*)(p + 110757888);
    float* ksum  = (float*)(p + 110905344);
    float* zbuf  = (float*)(p + 110921728);
    const size_t REQUIRED = 111052800;
    float* qpart = (float*)kvt;               // overlays kvt (dead until kvred)
    float* kpart = (float*)((char*)kvt + 262144);
    bf16*  qe    = (bf16*)out;                        // 32 MiB in d_out
    bf16*  kvpart= (bf16*)((char*)out + 33554432);    // 16 MiB bf16 partials
    bf16*  qb    = kb;                        // after splitk, kb dead
    bf16*  abuf  = (bf16*)(p + 0);            // xbT dead after attn
    bf16*  axbuf = (bf16*)(p + 33554432);     // qb dead after attn
    bf16*  tbuf  = (bf16*)(p + 67108864);     // vb dead after splitk

    if (ws_size < REQUIRED) {   // sentinel encodes actual ws size in MiB
        k_fill<<<(out_size + 255) / 256, 256, 0, stream>>>(out, out_size, 100000.0f + (float)(ws_size >> 20));
        return;
    }

    const long NC = (long)NDIM * CDIM;  // 2,097,152 elements per batch

    // setup (merged cvt3 + prep) + weight transposes + x transpose
    k_setup<<<1024, 256, 0, stream>>>(Wq, Wk, Wv, wqb, wkb, wvb, scale, invsc,
                                      dw_w, dwwT, bq, bk, bv, bqkv);
    k_transpose<<<dim3(32, 8, 1), 256, 0, stream>>>(fc1_w, fc1wT, 2048, 512, 0, 0);
    k_transpose<<<dim3(8, 32, 1), 256, 0, stream>>>(fc2_w, fc2wT, 512, 2048, 0, 0);
    k_transpose<<<dim3(64, 8, BATCH), 256, 0, stream>>>(x, xbT, 4096, 512, NC, NC);

    // fused conv q/k/v: one GEMM, A = [Wq;Wk;Wv] (1536x512), B staged once.
    // MFAST=1: M-tile-fastest swizzle -> 12 consecutive blocks reuse one B-panel.
    gemm_bt<EP_QKV, 128, 1><<<dim3(32, 12, 8), 256, 0, stream>>>(
        wqb, 512, 0, xbT, 512, NC, qe, 4096, NC, 512, bqkv, kb, 0, vb, 0);

    // k softmax chain, then both column-sum partials in one kernel
    k_krow<<<8192, 256, 0, stream>>>(kb, invsc);
    k_colsums<<<dim3(4, 16, 8), 256, 0, stream>>>(qe, kb, qpart, kpart);
    k_red2<<<32, 256, 0, stream>>>(qpart, qsum, kpart, ksum);

    // kv^T — split-K x4, bf16 partials in out[32M:48M] (qe untouched)
    gemm_tn_splitk<<<dim3(4, 4, 32), 256, 0, stream>>>(vb, 512, NC, kb, 512, NC, kvpart);
    k_kvred<<<1024, 256, 0, stream>>>(kvpart, kvt);

    // q chain (after splitk so qb can overlay kb) + fused z
    k_qrow<<<8192, 256, 0, stream>>>(qe, qsum, invsc, qb, ksum, zbuf);

    // enhanced = bf16(shortcut from xbT) + z*(q@kv)  -> overwrites all of `out`
    gemm_bt<EP_ATTN, 128, 0><<<dim3(4, 32, 8), 256, 0, stream>>>(
        qb, 512, NC, kvt, 512, 262144, out, 512, NC, 512, nullptr, xbT, NC, zbuf, 4096);

    // MixFFN: LN once over all rows, then 4 quarters over dead buffers
    k_ln512<<<8192, 256, 0, stream>>>(out, lnm_g, lnm_b, tbuf);
    for (int q4 = 0; q4 < 4; ++q4) {
        float* outq = out + (long)q4 * 8192 * CDIM;
        bf16* tq = tbuf + (long)q4 * 8192 * CDIM;
        gemm_bt<EP_BF16_BCOL, 128, 0><<<dim3(16, 64, 1), 256, 0, stream>>>(
            tq, 512, 0, fc1wT, 512, 0, abuf, 2048, 0, 512, fc1_b, nullptr, 0, nullptr, 0);
        k_dwlngelu4<<<2048, 256, 0, stream>>>(abuf, dwwT, dw_b, ln1_g, ln1_b, axbuf);
        gemm_bt<EP_OUT, 64, 0><<<dim3(4, 128, 1), 256, 0, stream>>>(
            axbuf, 2048, 0, fc2wT, 2048, 0, outq, 512, 0, 2048, fc2_b, outq, 0, nullptr, 0);
    }
}

// Round 10
// 613.154 us; speedup vs baseline: 1.0507x; 1.0306x over previous
//
#include <hip/hip_runtime.h>
#include <hip/hip_bf16.h>

typedef __hip_bfloat16 bf16;
typedef __attribute__((ext_vector_type(8))) short bh8;      // 8 x bf16 bits
typedef __attribute__((ext_vector_type(4))) float f32x4;

#define CDIM 512
#define NDIM 4096
#define HIDD 2048
#define BATCH 8

__device__ __forceinline__ float bf2f(short s) {
    union { unsigned u; float f; } c; c.u = ((unsigned)(unsigned short)s) << 16; return c.f;
}
__device__ __forceinline__ short f2bf(float f) {
    union { __hip_bfloat16 h; short s; } c; c.h = __float2bfloat16(f); return c.s;
}
__device__ __forceinline__ float wsum(float v) {
#pragma unroll
    for (int o = 32; o; o >>= 1) v += __shfl_xor(v, o);
    return v;
}
__device__ __forceinline__ float wmax(float v) {
#pragma unroll
    for (int o = 32; o; o >>= 1) v = fmaxf(v, __shfl_xor(v, o));
    return v;
}

#define GLL(g, l) __builtin_amdgcn_global_load_lds( \
    (const __attribute__((address_space(1))) unsigned int*)(g), \
    (__attribute__((address_space(3))) unsigned int*)(l), 16, 0, 0)

// ---------------------------------------------------------------- GEMM (NT)
// C[M,N] = A(M,K) @ Bt(N,K)^T, row-major bf16, fp32 accum. TMx128 tile, BK=64.
// LDS tiles XOR-swizzled (pre-swizzled GLL source + swizzled fragment read).
// bf16-output modes use an LDS-transposed epilogue: full-line dwordx4 stores.
enum { EP_BF16_BROW = 1, EP_ATTN = 3, EP_BF16_BCOL = 4, EP_OUT = 5, EP_QKV = 6 };

template<int MODE, int TM, int MFAST>
__global__ __launch_bounds__(256)
void gemm_bt(const bf16* __restrict__ A, int lda, long sA,
             const bf16* __restrict__ Bt, int ldb, long sB,
             void* __restrict__ Cp, int ldc, long sC, int K,
             const float* __restrict__ bias,
             const void* __restrict__ aux1, long sAux1,
             const void* __restrict__ aux2, long sAux2)
{
    constexpr int MF = TM / 32;                 // A-frags per wave; also A-chunks/thread
    __shared__ __align__(16) bf16 smem[TM * 64 + 128 * 64];   // As | Bs (contiguous)
    bf16* As = smem;
    bf16* Bs = smem + TM * 64;
    int bx, by, bz;
    {
        const int gx = gridDim.x, gy = gridDim.y;
        const int nwg = gx * gy * gridDim.z;
        int lid = blockIdx.x + gx * (blockIdx.y + gy * blockIdx.z);
        const int cpx = nwg >> 3;
        int swz = (lid & 7) * cpx + (lid >> 3);
        if constexpr (MFAST) {
            by = swz % gy; swz /= gy;           // M-tile fastest: B-panel reuse
            bx = swz % gx;
            bz = swz / gx;
        } else {
            bx = swz % gx; swz /= gx;
            by = swz % gy;
            bz = swz / gy;
        }
    }
    const bf16* Ab = A + (long)bz * sA + (long)by * TM * lda;
    const bf16* Bb = Bt + (long)bz * sB + (long)bx * 128 * ldb;
    const int t = threadIdx.x, lane = t & 63, wid = t >> 6;
    const int wm = wid >> 1, wn = wid & 1, lg = lane >> 4, lr = lane & 15;

    f32x4 acc[MF][4];
#pragma unroll
    for (int m = 0; m < MF; ++m)
#pragma unroll
        for (int n = 0; n < 4; ++n) acc[m][n] = (f32x4){0.f, 0.f, 0.f, 0.f};

    for (int kt = 0; kt < K; kt += 64) {
#pragma unroll
        for (int i = 0; i < MF; ++i) {
            const int ch = i * 256 + t;
            const int row = ch >> 3;
            const int cs = (ch & 7) ^ (row & 7);    // pre-swizzled source chunk
            GLL(Ab + (long)row * lda + kt + (cs << 3), (char*)As + i * 4096 + wid * 1024);
        }
#pragma unroll
        for (int i = 0; i < 4; ++i) {
            const int ch = i * 256 + t;
            const int row = ch >> 3;
            const int cs = (ch & 7) ^ (row & 7);
            GLL(Bb + (long)row * ldb + kt + (cs << 3), (char*)Bs + i * 4096 + wid * 1024);
        }
        __syncthreads();
#pragma unroll
        for (int kk = 0; kk < 2; ++kk) {
            bh8 af[MF], bfv[4];
#pragma unroll
            for (int m = 0; m < MF; ++m) {
                const int row = wm * (TM / 2) + m * 16 + lr;
                const int kc = (kk * 4 + lg) ^ (row & 7);
                af[m] = *(const bh8*)(As + row * 64 + kc * 8);
            }
#pragma unroll
            for (int n = 0; n < 4; ++n) {
                const int row = wn * 64 + n * 16 + lr;
                const int kc = (kk * 4 + lg) ^ (row & 7);
                bfv[n] = *(const bh8*)(Bs + row * 64 + kc * 8);
            }
#pragma unroll
            for (int m = 0; m < MF; ++m)
#pragma unroll
                for (int n = 0; n < 4; ++n)
                    acc[m][n] = __builtin_amdgcn_mfma_f32_16x16x32_bf16(af[m], bfv[n], acc[m][n], 0, 0, 0);
        }
        __syncthreads();
    }

    if constexpr (TM == 128 && (MODE == EP_QKV || MODE == EP_BF16_BCOL)) {
        // LDS-transposed epilogue: scatter acc (swizzled) -> gather bh8 -> full-line stores
        bf16* Cs = smem;                         // As|Bs dead; 32 KiB = 128x128 bf16
        bf16* dstb;
        bool doexp = false;
        if constexpr (MODE == EP_QKV) {
            const int which = by >> 2;           // 4 M-tiles per 512-row segment
            if (which == 0) { dstb = (bf16*)Cp; doexp = true; }
            else if (which == 1) dstb = (bf16*)aux1;
            else dstb = (bf16*)aux2;
            dstb += (long)bz * sC + (long)((by & 3) * 128) * ldc;
        } else {
            dstb = (bf16*)Cp + (long)bz * sC + (long)by * 128 * ldc;
        }
#pragma unroll
        for (int m = 0; m < MF; ++m)
#pragma unroll
            for (int n = 0; n < 4; ++n)
#pragma unroll
                for (int r = 0; r < 4; ++r) {
                    const int row = wm * 64 + m * 16 + lg * 4 + r;
                    const int col = wn * 64 + n * 16 + lr;
                    float v = acc[m][n][r];
                    if constexpr (MODE == EP_QKV) v += bias[by * 128 + row];
                    else v += bias[bx * 128 + col];
                    if (doexp) v = __expf(v);
                    Cs[row * 128 + (col ^ (((row >> 2) & 3) << 4))] = __float2bfloat16(v);
                }
        __syncthreads();
#pragma unroll
        for (int it = 0; it < 8; ++it) {
            const int id = it * 256 + t;
            const int row = id >> 4, colc = (id & 15) << 3;
            bh8 v = *(const bh8*)(Cs + row * 128 + (colc ^ (((row >> 2) & 3) << 4)));
            *(bh8*)(dstb + (long)row * ldc + bx * 128 + colc) = v;
        }
        return;
    }

    const int gr0 = by * TM + wm * (TM / 2);
    const int gc0 = bx * 128 + wn * 64;
#pragma unroll
    for (int m = 0; m < MF; ++m) {
#pragma unroll
        for (int n = 0; n < 4; ++n) {
            const int gc = gc0 + n * 16 + lr;
#pragma unroll
            for (int r = 0; r < 4; ++r) {
                const int gr = gr0 + m * 16 + lg * 4 + r;
                float v = acc[m][n][r];
                if constexpr (MODE == EP_BF16_BROW) {
                    ((bf16*)Cp + (long)bz * sC)[(long)gr * ldc + gc] = __float2bfloat16(v + bias[gr]);
                } else if constexpr (MODE == EP_ATTN) {
                    // shortcut from xbT (bf16, (N,C) row-major -> coalesced)
                    const bf16* xg = (const bf16*)aux1 + (long)bz * sAux1;
                    const float* zg = (const float*)aux2 + (long)bz * sAux2;   // z[b] (N)
                    ((float*)Cp + (long)bz * sC)[(long)gr * ldc + gc] =
                        zg[gr] * v + bf2f(*(const short*)(xg + (long)gr * 512 + gc));
                } else if constexpr (MODE == EP_OUT) {
                    float* op = (float*)Cp;
                    const long idx = (long)gr * ldc + gc;
                    op[idx] = v + bias[gc] + ((const float*)aux1)[idx];
                }
            }
        }
    }
}

// ---------------------------------------------------------------- GEMM (TN, split-K x4)
// part[b,ks] (512x512 bf16) = A[b,ks-chunk]^T @ B[b,ks-chunk]; A,B: (4096x512) row-major.
__global__ __launch_bounds__(256)
void gemm_tn_splitk(const bf16* __restrict__ A, int lda, long sA,
                    const bf16* __restrict__ B, int ldb, long sB,
                    bf16* __restrict__ part)
{
    __shared__ __align__(16) short smem[2 * 64 * 128];   // As | Bs (contiguous, 32 KiB)
    short* As = smem;
    short* Bs = smem + 64 * 128;
    int bx, by, bzl;
    {
        const int gx = gridDim.x, gy = gridDim.y;
        const int nwg = gx * gy * gridDim.z;
        int lid = blockIdx.x + gx * (blockIdx.y + gy * blockIdx.z);
        const int cpx = nwg >> 3;
        int swz = (lid & 7) * cpx + (lid >> 3);
        bx = swz % gx; swz /= gx;
        by = swz % gy;
        bzl = swz / gy;
    }
    const int bz = bzl >> 2, ks = bzl & 3;
    const bf16* Ab = A + (long)bz * sA + (long)ks * 1024 * lda + by * 128;
    const bf16* Bb = B + (long)bz * sB + (long)ks * 1024 * ldb + bx * 128;
    const int t = threadIdx.x, lane = t & 63, wid = t >> 6;
    const int wm = wid >> 1, wn = wid & 1, lg = lane >> 4, lr = lane & 15;

    f32x4 acc[4][4];
#pragma unroll
    for (int m = 0; m < 4; ++m)
#pragma unroll
        for (int n = 0; n < 4; ++n) acc[m][n] = (f32x4){0.f, 0.f, 0.f, 0.f};

    for (int kt = 0; kt < 1024; kt += 64) {
#pragma unroll
        for (int i = 0; i < 4; ++i) {
            const int ch = i * 256 + t;                 // linear 16B-chunk id
            const int row = ch >> 4;                    // k within tile
            const int cs = (ch & 15) ^ (((row >> 3) & 3) << 1);  // swizzled src chunk
            GLL(Ab + (long)(kt + row) * lda + (cs << 3), (char*)As + i * 4096 + wid * 1024);
            GLL(Bb + (long)(kt + row) * ldb + (cs << 3), (char*)Bs + i * 4096 + wid * 1024);
        }
        __syncthreads();
#pragma unroll
        for (int kk = 0; kk < 2; ++kk) {
            bh8 af[4], bfv[4];
#pragma unroll
            for (int m = 0; m < 4; ++m) {
                const int col = wm * 64 + m * 16 + lr;
#pragma unroll
                for (int u = 0; u < 8; ++u) {
                    const int row = kk * 32 + lg * 8 + u;
                    af[m][u] = As[row * 128 + (((col >> 3) ^ (((row >> 3) & 3) << 1)) << 3) + (col & 7)];
                }
            }
#pragma unroll
            for (int n = 0; n < 4; ++n) {
                const int col = wn * 64 + n * 16 + lr;
#pragma unroll
                for (int u = 0; u < 8; ++u) {
                    const int row = kk * 32 + lg * 8 + u;
                    bfv[n][u] = Bs[row * 128 + (((col >> 3) ^ (((row >> 3) & 3) << 1)) << 3) + (col & 7)];
                }
            }
#pragma unroll
            for (int m = 0; m < 4; ++m)
#pragma unroll
                for (int n = 0; n < 4; ++n)
                    acc[m][n] = __builtin_amdgcn_mfma_f32_16x16x32_bf16(af[m], bfv[n], acc[m][n], 0, 0, 0);
        }
        __syncthreads();
    }

    // LDS-transposed epilogue (full-line bh8 stores)
    bf16* Cs = (bf16*)smem;
    bf16* dstb = part + ((long)bzl << 18) + (long)by * 128 * 512;
#pragma unroll
    for (int m = 0; m < 4; ++m)
#pragma unroll
        for (int n = 0; n < 4; ++n)
#pragma unroll
            for (int r = 0; r < 4; ++r) {
                const int row = wm * 64 + m * 16 + lg * 4 + r;
                const int col = wn * 64 + n * 16 + lr;
                Cs[row * 128 + (col ^ (((row >> 2) & 3) << 4))] = __float2bfloat16(acc[m][n][r]);
            }
    __syncthreads();
#pragma unroll
    for (int it = 0; it < 8; ++it) {
        const int id = it * 256 + t;
        const int row = id >> 4, colc = (id & 15) << 3;
        bh8 v = *(const bh8*)(Cs + row * 128 + (colc ^ (((row >> 2) & 3) << 4)));
        *(bh8*)(dstb + (long)row * 512 + bx * 128 + colc) = v;
    }
}

// ---------------------------------------------------------------- merged transposes
// bid<256: fc1_w (512x2048)->(2048x512); <512: fc2_w (2048x512)->(512x2048);
// else: x (B,512,4096)->(B,4096,512) bf16.
__global__ __launch_bounds__(256)
void k_transpose3(const float* __restrict__ fc1w, bf16* __restrict__ fc1wT,
                  const float* __restrict__ fc2w, bf16* __restrict__ fc2wT,
                  const float* __restrict__ x, bf16* __restrict__ xbT)
{
    __shared__ float tile[64][65];
    const int bid = blockIdx.x;
    const float* s; bf16* d; int Rd, Cd, bx, by;
    if (bid < 256) {
        s = fc1w; d = fc1wT; Rd = 2048; Cd = 512; bx = bid & 31; by = bid >> 5;
    } else if (bid < 512) {
        const int i = bid - 256;
        s = fc2w; d = fc2wT; Rd = 512; Cd = 2048; bx = i & 7; by = i >> 3;
    } else {
        const int i = bid - 512;
        const int bz = i >> 9, j = i & 511;
        bx = j & 63; by = j >> 6;
        const long NC = (long)NDIM * CDIM;
        s = x + (long)bz * NC; d = xbT + (long)bz * NC; Rd = 4096; Cd = 512;
    }
    const int r0 = bx * 64, c0 = by * 64;
    const int t = threadIdx.x;
#pragma unroll 4
    for (int i = 0; i < 16; ++i) {
        int idx = i * 256 + t;
        int a = idx >> 6, b = idx & 63;
        tile[a][b] = s[(long)(c0 + a) * Rd + r0 + b];
    }
    __syncthreads();
#pragma unroll 4
    for (int i = 0; i < 16; ++i) {
        int idx = i * 256 + t;
        int a = idx >> 6, b = idx & 63;
        d[(long)(r0 + a) * Cd + c0 + b] = __float2bfloat16(tile[b][a]);
    }
}

// one-shot setup: conv-weight cvt (3x), invsc, qkv bias, dw-weight transpose
__global__ void k_setup(const float* __restrict__ Wq, const float* __restrict__ Wk,
                        const float* __restrict__ Wv, bf16* __restrict__ oq,
                        bf16* __restrict__ ok, bf16* __restrict__ ov,
                        const float* __restrict__ scale, float* __restrict__ invsc,
                        const float* __restrict__ w, float* __restrict__ wT,
                        const float* __restrict__ bq, const float* __restrict__ bk,
                        const float* __restrict__ bv, float* __restrict__ bqkv) {
    int i = blockIdx.x * 256 + threadIdx.x;
    if (i < 262144) {
        oq[i] = __float2bfloat16(Wq[i]);
        ok[i] = __float2bfloat16(Wk[i]);
        ov[i] = __float2bfloat16(Wv[i]);
    }
    if (i < 512) invsc[i] = 1.0f / log1pf(expf(scale[i]));
    if (i < 1536) bqkv[i] = (i < 512 ? bq[i] : (i < 1024 ? bk[i - 512] : bv[i - 1024]));
    if (i < HIDD * 9) {
        int chn = i / 9, kk = i % 9;
        wT[kk * HIDD + chn] = w[i];
    }
}

__global__ void k_fill(float* o, int n, float v) {
    int i = blockIdx.x * 256 + threadIdx.x; if (i < n) o[i] = v;
}

// ------------------------------------------------- combined column partial sums
// x<2: qe columns; x>=2: kb columns. Each thread sums 256 rows of one column.
__global__ __launch_bounds__(256)
void k_colsums(const bf16* __restrict__ qe, const bf16* __restrict__ kb,
               float* __restrict__ qpart, float* __restrict__ kpart) {
    const int xb = blockIdx.x;                     // 0..3
    const int ic = blockIdx.y, b = blockIdx.z;     // 16 chunks of 256 rows
    const int j = (xb & 1) * 256 + threadIdx.x;
    const bf16* src = (xb < 2) ? qe : kb;
    const bf16* p = src + (long)b * (NDIM * CDIM) + (long)ic * 256 * CDIM + j;
    float s = 0.f;
    for (int i = 0; i < 256; ++i) s += bf2f(*(const short*)(p + (long)i * CDIM));
    ((xb < 2) ? qpart : kpart)[((long)b * 16 + ic) * CDIM + j] = s;
}

// combined second-stage reduce: qsum (idx<4096) and ksum (idx>=4096)
__global__ __launch_bounds__(256)
void k_red2(const float* __restrict__ qpart, float* __restrict__ qsum,
            const float* __restrict__ kpart, float* __restrict__ ksum) {
    const int idx = blockIdx.x * 256 + threadIdx.x;  // 8192
    const int which = idx >> 12, r = idx & 4095;
    const int b = r >> 9, c = r & 511;
    const float* src = which ? kpart : qpart;
    float s = 0.f;
#pragma unroll
    for (int jc = 0; jc < 16; ++jc) s += src[((long)(b * 16 + jc)) * CDIM + c];
    (which ? ksum : qsum)[r] = s;
}

// merged: bid<1024 -> kvt reduce; else q row pass + fused z
__global__ __launch_bounds__(256)
void k_kvqrow(const bf16* __restrict__ part, bf16* __restrict__ kvt,
              const bf16* __restrict__ qe, const float* __restrict__ qsum,
              const float* __restrict__ invsc, bf16* __restrict__ qb,
              const float* __restrict__ ksum, float* __restrict__ z)
{
    if (blockIdx.x < 1024) {
        const long e = ((long)blockIdx.x * 256 + threadIdx.x) * 8;
        const int b = (int)(e >> 18);
        const int off = (int)(e & 262143);
        float s[8] = {0.f, 0.f, 0.f, 0.f, 0.f, 0.f, 0.f, 0.f};
#pragma unroll
        for (int ks = 0; ks < 4; ++ks) {
            bh8 v = *(const bh8*)(part + (((long)(b * 4 + ks)) << 18) + off);
#pragma unroll
            for (int j = 0; j < 8; ++j) s[j] += bf2f(v[j]);
        }
        bh8 o;
#pragma unroll
        for (int j = 0; j < 8; ++j) o[j] = f2bf(s[j]);
        *(bh8*)(kvt + ((long)b << 18) + off) = o;
        return;
    }
    const long row = (long)(blockIdx.x - 1024) * 4 + (threadIdx.x >> 6);
    const int lane = threadIdx.x & 63;
    const int b = (int)(row >> 12);
    bh8 ev = *(const bh8*)(qe + row * CDIM + lane * 8);
    const float* qs = qsum + b * CDIM + lane * 8;
    const float* is = invsc + lane * 8;
    f32x4 s0 = *(const f32x4*)qs, s1 = *(const f32x4*)(qs + 4);
    f32x4 i0 = *(const f32x4*)is, i1 = *(const f32x4*)(is + 4);
    float q[8];
#pragma unroll
    for (int k = 0; k < 4; ++k) {
        q[k]     = (bf2f(ev[k]) / s0[k] + 1e-6f) * i0[k];
        q[k + 4] = (bf2f(ev[k + 4]) / s1[k] + 1e-6f) * i1[k];
    }
    float s2 = 0.f, s6 = 0.f, q3[8];
#pragma unroll
    for (int k = 0; k < 8; ++k) { s2 += q[k] * q[k]; float c = q[k] * q[k] * q[k]; q3[k] = c; s6 += c * c; }
    s2 = wsum(s2); s6 = wsum(s6);
    const float sc = sqrtf(s2) / sqrtf(s6);
    bh8 o;
#pragma unroll
    for (int k = 0; k < 8; ++k) o[k] = f2bf(q3[k] * sc);
    *(bh8*)(qb + row * CDIM + lane * 8) = o;
    // fused z
    const float* ks = ksum + (long)b * CDIM + lane * 8;
    f32x4 k0 = *(const f32x4*)ks, k1 = *(const f32x4*)(ks + 4);
    float zd = 0.f;
#pragma unroll
    for (int j = 0; j < 4; ++j) { zd += bf2f(o[j]) * k0[j]; zd += bf2f(o[j + 4]) * k1[j]; }
    zd = wsum(zd);
    if (lane == 0) z[row] = 1.0f / (zd + 1e-6f);
}

// k row pass (IN-PLACE, bf16): row softmax (axis=2), /sc, cube, renorm.
__global__ __launch_bounds__(256)
void k_krow(bf16* __restrict__ kb, const float* __restrict__ invsc)
{
    const long row = (long)blockIdx.x * 4 + (threadIdx.x >> 6);
    const int lane = threadIdx.x & 63;
    bh8 v = *(const bh8*)(kb + row * CDIM + lane * 8);
    const float* is = invsc + lane * 8;
    f32x4 i0 = *(const f32x4*)is, i1 = *(const f32x4*)(is + 4);
    float xv[8];
#pragma unroll
    for (int k = 0; k < 8; ++k) xv[k] = bf2f(v[k]);
    float mx = -1e30f;
#pragma unroll
    for (int k = 0; k < 8; ++k) mx = fmaxf(mx, xv[k]);
    mx = wmax(mx);
    float e[8], se = 0.f;
#pragma unroll
    for (int k = 0; k < 8; ++k) { e[k] = __expf(xv[k] - mx); se += e[k]; }
    se = wsum(se);
    const float inv = 1.0f / se;
    float q[8];
#pragma unroll
    for (int k = 0; k < 4; ++k) {
        q[k]     = (e[k] * inv + 1e-6f) * i0[k];
        q[k + 4] = (e[k + 4] * inv + 1e-6f) * i1[k];
    }
    float s2 = 0.f, s6 = 0.f, q3[8];
#pragma unroll
    for (int k = 0; k < 8; ++k) { s2 += q[k] * q[k]; float c = q[k] * q[k] * q[k]; q3[k] = c; s6 += c * c; }
    s2 = wsum(s2); s6 = wsum(s6);
    const float sc = sqrtf(s2) / sqrtf(s6);
    bh8 o;
#pragma unroll
    for (int k = 0; k < 8; ++k) o[k] = f2bf(q3[k] * sc);
    *(bh8*)(kb + row * CDIM + lane * 8) = o;
}

// LN over 512 (lnm), fp32 in -> bf16 out. 1 wave/row.
__global__ __launch_bounds__(256)
void k_ln512(const float* __restrict__ src, const float* __restrict__ g,
             const float* __restrict__ bta, bf16* __restrict__ dst)
{
    const long row = (long)blockIdx.x * 4 + (threadIdx.x >> 6);
    const int lane = threadIdx.x & 63;
    const float* p = src + row * CDIM + lane * 8;
    f32x4 a0 = *(const f32x4*)p, a1 = *(const f32x4*)(p + 4);
    float s = 0.f, ss = 0.f;
#pragma unroll
    for (int k = 0; k < 4; ++k) { s += a0[k] + a1[k]; ss += a0[k] * a0[k] + a1[k] * a1[k]; }
    s = wsum(s); ss = wsum(ss);
    const float mean = s * (1.0f / 512), var = ss * (1.0f / 512) - mean * mean;
    const float rstd = rsqrtf(var + 1e-5f);
    const float* gp = g + lane * 8;
    const float* bp = bta + lane * 8;
    f32x4 g0 = *(const f32x4*)gp, g1 = *(const f32x4*)(gp + 4);
    f32x4 b0 = *(const f32x4*)bp, b1 = *(const f32x4*)(bp + 4);
    bh8 o;
#pragma unroll
    for (int k = 0; k < 4; ++k) {
        o[k]     = f2bf((a0[k] - mean) * rstd * g0[k] + b0[k]);
        o[k + 4] = f2bf((a1[k] - mean) * rstd * g1[k] + b1[k]);
    }
    *(bh8*)(dst + row * CDIM + lane * 8) = o;
}

// depthwise 3x3 (SAME) + skip + LN(2048) + exact GELU.
__global__ __launch_bounds__(256)
void k_dwlngelu4(const bf16* __restrict__ a, const float* __restrict__ dwwT,
                 const float* __restrict__ dwb, const float* __restrict__ g1,
                 const float* __restrict__ b1, bf16* __restrict__ ax)
{
    const long s0 = (long)blockIdx.x * 4;       // quad-base token (quarter-local)
    const int h = (int)((s0 >> 6) & 63);
    const int w0 = (int)(s0 & 63);
    const int ch = threadIdx.x * 8;

    float wgt[9][8];
#pragma unroll
    for (int kk = 0; kk < 9; ++kk) {
        f32x4 w0v = *(const f32x4*)(dwwT + kk * HIDD + ch);
        f32x4 w1v = *(const f32x4*)(dwwT + kk * HIDD + ch + 4);
#pragma unroll
        for (int j = 0; j < 4; ++j) { wgt[kk][j] = w0v[j]; wgt[kk][j + 4] = w1v[j]; }
    }
#pragma unroll
    for (int j = 0; j < 8; ++j) wgt[4][j] += 1.0f;   // fold the skip (dw + a)

    float acc[4][8];
    {
        f32x4 d0 = *(const f32x4*)(dwb + ch), d1 = *(const f32x4*)(dwb + ch + 4);
#pragma unroll
        for (int ti = 0; ti < 4; ++ti)
#pragma unroll
            for (int j = 0; j < 4; ++j) { acc[ti][j] = d0[j]; acc[ti][j + 4] = d1[j]; }
    }

#pragma unroll
    for (int dy = -1; dy <= 1; ++dy) {
        const int hh = h + dy;
        if ((unsigned)hh >= 64u) continue;       // wave-uniform
#pragma unroll
        for (int c = -1; c <= 4; ++c) {
            const int ww = w0 + c;
            if ((unsigned)ww >= 64u) continue;   // wave-uniform
            bh8 v = *(const bh8*)(a + (s0 + (long)dy * 64 + c) * HIDD + ch);
            float f[8];
#pragma unroll
            for (int j = 0; j < 8; ++j) f[j] = bf2f(v[j]);
#pragma unroll
            for (int ti = 0; ti < 4; ++ti) {
                const int dx = c - ti;
                if (dx < -1 || dx > 1) continue;
                const int kk = (dy + 1) * 3 + (dx + 1);
#pragma unroll
                for (int j = 0; j < 8; ++j) acc[ti][j] += wgt[kk][j] * f[j];
            }
        }
    }

    // LN(2048) per token
    float sv[4], qv[4];
#pragma unroll
    for (int ti = 0; ti < 4; ++ti) {
        float s = 0.f, q = 0.f;
#pragma unroll
        for (int j = 0; j < 8; ++j) { s += acc[ti][j]; q += acc[ti][j] * acc[ti][j]; }
        sv[ti] = wsum(s); qv[ti] = wsum(q);
    }
    __shared__ float red[4][4][2];
    const int wid = threadIdx.x >> 6, lane = threadIdx.x & 63;
    if (lane == 0)
#pragma unroll
        for (int ti = 0; ti < 4; ++ti) { red[wid][ti][0] = sv[ti]; red[wid][ti][1] = qv[ti]; }
    __syncthreads();

    f32x4 ga = *(const f32x4*)(g1 + ch), gb = *(const f32x4*)(g1 + ch + 4);
    f32x4 ba = *(const f32x4*)(b1 + ch), bb = *(const f32x4*)(b1 + ch + 4);
    float gg[8], bb8[8];
#pragma unroll
    for (int j = 0; j < 4; ++j) { gg[j] = ga[j]; gg[j + 4] = gb[j]; bb8[j] = ba[j]; bb8[j + 4] = bb[j]; }

#pragma unroll
    for (int ti = 0; ti < 4; ++ti) {
        const float s = red[0][ti][0] + red[1][ti][0] + red[2][ti][0] + red[3][ti][0];
        const float q = red[0][ti][1] + red[1][ti][1] + red[2][ti][1] + red[3][ti][1];
        const float mean = s * (1.0f / 2048), var = q * (1.0f / 2048) - mean * mean;
        const float rstd = rsqrtf(var + 1e-5f);
        bh8 o;
#pragma unroll
        for (int j = 0; j < 8; ++j) {
            float y = (acc[ti][j] - mean) * rstd * gg[j] + bb8[j];
            o[j] = f2bf(0.5f * y * (1.0f + erff(y * 0.70710678118654752f)));
        }
        *(bh8*)(ax + (s0 + ti) * HIDD + ch) = o;
    }
}

// ---------------------------------------------------------------- launch
extern "C" void kernel_launch(void* const* d_in, const int* in_sizes, int n_in,
                              void* d_out, int out_size, void* d_ws, size_t ws_size,
                              hipStream_t stream) {
    const float* x     = (const float*)d_in[0];
    const float* Wq    = (const float*)d_in[1];
    const float* bq    = (const float*)d_in[2];
    const float* Wk    = (const float*)d_in[3];
    const float* bk    = (const float*)d_in[4];
    const float* Wv    = (const float*)d_in[5];
    const float* bv    = (const float*)d_in[6];
    const float* scale = (const float*)d_in[7];
    const float* fc1_w = (const float*)d_in[8];
    const float* fc1_b = (const float*)d_in[9];
    const float* dw_w  = (const float*)d_in[10];
    const float* dw_b  = (const float*)d_in[11];
    const float* fc2_w = (const float*)d_in[12];
    const float* fc2_b = (const float*)d_in[13];
    const float* ln1_g = (const float*)d_in[14];
    const float* ln1_b = (const float*)d_in[15];
    const float* lnm_g = (const float*)d_in[16];
    const float* lnm_b = (const float*)d_in[17];
    float* out = (float*)d_out;
    char* p = (char*)d_ws;

    // ---- workspace layout ----
    bf16*  xbT   = (bf16*)(p + 0);            // 32 MiB, alive through EP_ATTN
    bf16*  kb    = (bf16*)(p + 33554432);     // conv-k -> qb -> axbuf
    bf16*  vb    = (bf16*)(p + 67108864);     // conv-v -> tbuf
    bf16*  kvt   = (bf16*)(p + 100663296);    //  4 MiB
    bf16*  wqb   = (bf16*)(p + 104857600);    // wqb|wkb|wvb contiguous = 1536x512
    bf16*  wkb   = (bf16*)(p + 105381888);
    bf16*  wvb   = (bf16*)(p + 105906176);
    bf16*  fc1wT = (bf16*)(p + 106430464);    //  2 MiB
    bf16*  fc2wT = (bf16*)(p + 108527616);    //  2 MiB
    float* invsc = (float*)(p + 110624768);
    float* dwwT  = (float*)(p + 110626816);   // 73,728 B
    float* bqkv  = (float*)(p + 110700544);   //  6,144 B
    float* qsum  = (float*)(p + 110757888);
    float* ksum  = (float*)(p + 110905344);
    float* zbuf  = (float*)(p + 110921728);
    const size_t REQUIRED = 111052800;
    float* qpart = (float*)kvt;               // overlays kvt (dead until kvred)
    float* kpart = (float*)((char*)kvt + 262144);
    bf16*  qe    = (bf16*)out;                        // 32 MiB in d_out
    bf16*  kvpart= (bf16*)((char*)out + 33554432);    // 16 MiB bf16 partials
    bf16*  qb    = kb;                        // after splitk, kb dead
    bf16*  abuf  = (bf16*)(p + 0);            // xbT dead after attn
    bf16*  axbuf = (bf16*)(p + 33554432);     // qb dead after attn
    bf16*  tbuf  = (bf16*)(p + 67108864);     // vb dead after splitk

    if (ws_size < REQUIRED) {   // sentinel encodes actual ws size in MiB
        k_fill<<<(out_size + 255) / 256, 256, 0, stream>>>(out, out_size, 100000.0f + (float)(ws_size >> 20));
        return;
    }

    const long NC = (long)NDIM * CDIM;  // 2,097,152 elements per batch

    // setup + all transposes (merged)
    k_setup<<<1024, 256, 0, stream>>>(Wq, Wk, Wv, wqb, wkb, wvb, scale, invsc,
                                      dw_w, dwwT, bq, bk, bv, bqkv);
    k_transpose3<<<4608, 256, 0, stream>>>(fc1_w, fc1wT, fc2_w, fc2wT, x, xbT);

    // fused conv q/k/v: one GEMM, A = [Wq;Wk;Wv] (1536x512), B staged once.
    gemm_bt<EP_QKV, 128, 1><<<dim3(32, 12, 8), 256, 0, stream>>>(
        wqb, 512, 0, xbT, 512, NC, qe, 4096, NC, 512, bqkv, kb, 0, vb, 0);

    // k softmax chain, then both column-sum partials in one kernel
    k_krow<<<8192, 256, 0, stream>>>(kb, invsc);
    k_colsums<<<dim3(4, 16, 8), 256, 0, stream>>>(qe, kb, qpart, kpart);
    k_red2<<<32, 256, 0, stream>>>(qpart, qsum, kpart, ksum);

    // kv^T — split-K x4, bf16 partials in out[32M:48M] (qe untouched)
    gemm_tn_splitk<<<dim3(4, 4, 32), 256, 0, stream>>>(vb, 512, NC, kb, 512, NC, kvpart);
    // kvt reduce + q chain + fused z (merged; independent work, grid split)
    k_kvqrow<<<9216, 256, 0, stream>>>(kvpart, kvt, qe, qsum, invsc, qb, ksum, zbuf);

    // enhanced = bf16(shortcut from xbT) + z*(q@kv)  -> overwrites all of `out`
    gemm_bt<EP_ATTN, 128, 0><<<dim3(4, 32, 8), 256, 0, stream>>>(
        qb, 512, NC, kvt, 512, 262144, out, 512, NC, 512, nullptr, xbT, NC, zbuf, 4096);

    // MixFFN: LN once over all rows, then 4 quarters over dead buffers
    k_ln512<<<8192, 256, 0, stream>>>(out, lnm_g, lnm_b, tbuf);
    for (int q4 = 0; q4 < 4; ++q4) {
        float* outq = out + (long)q4 * 8192 * CDIM;
        bf16* tq = tbuf + (long)q4 * 8192 * CDIM;
        gemm_bt<EP_BF16_BCOL, 128, 0><<<dim3(16, 64, 1), 256, 0, stream>>>(
            tq, 512, 0, fc1wT, 512, 0, abuf, 2048, 0, 512, fc1_b, nullptr, 0, nullptr, 0);
        k_dwlngelu4<<<2048, 256, 0, stream>>>(abuf, dwwT, dw_b, ln1_g, ln1_b, axbuf);
        gemm_bt<EP_OUT, 64, 0><<<dim3(4, 128, 1), 256, 0, stream>>>(
            axbuf, 2048, 0, fc2wT, 2048, 0, outq, 512, 0, 2048, fc2_b, outq, 0, nullptr, 0);
    }
}

// Round 11
// 573.890 us; speedup vs baseline: 1.1226x; 1.0684x over previous
//
#include <hip/hip_runtime.h>
#include <hip/hip_bf16.h>

typedef __hip_bfloat16 bf16;
typedef __attribute__((ext_vector_type(8))) short bh8;      // 8 x bf16 bits
typedef __attribute__((ext_vector_type(4))) float f32x4;

#define CDIM 512
#define NDIM 4096
#define HIDD 2048
#define BATCH 8

__device__ __forceinline__ float bf2f(short s) {
    union { unsigned u; float f; } c; c.u = ((unsigned)(unsigned short)s) << 16; return c.f;
}
__device__ __forceinline__ short f2bf(float f) {
    union { __hip_bfloat16 h; short s; } c; c.h = __float2bfloat16(f); return c.s;
}
__device__ __forceinline__ float wsum(float v) {
#pragma unroll
    for (int o = 32; o; o >>= 1) v += __shfl_xor(v, o);
    return v;
}
__device__ __forceinline__ float wmax(float v) {
#pragma unroll
    for (int o = 32; o; o >>= 1) v = fmaxf(v, __shfl_xor(v, o));
    return v;
}

#define GLL(g, l) __builtin_amdgcn_global_load_lds( \
    (const __attribute__((address_space(1))) unsigned int*)(g), \
    (__attribute__((address_space(3))) unsigned int*)(l), 16, 0, 0)

// ================================================================ gemm256
// 256x256 tile, BK=64, 512 threads = 8 waves (2M x 4N), per-wave 128x64 out.
// 8-phase-style K-loop: counted vmcnt (never 0 in main loop), raw barriers,
// setprio around MFMA clusters. LDS 128 KiB double-buffered, XOR-swizzled
// staging (pre-swizzled global source + XOR fragment reads) - conflict-free.
// Accumulation order identical to the 128^2 kernel -> bitwise-identical C.
// MODE: 0 = QKV (3-way dest split, exp on q), 1 = fc1 (bias[col], bf16 out).

// stage one half-tile (128 rows x 64 cols) of the next K-tile; 2 GLL/thread.
__device__ __forceinline__ void stage_ht(const bf16* __restrict__ base, int ld,
                                         int kt, char* ldsb, int t) {
#pragma unroll
    for (int l = 0; l < 2; ++l) {
        const int id = l * 512 + t;
        const int row = id >> 3, c = id & 7;
        const int cs = c ^ (row & 7);
        GLL(base + (long)row * ld + kt + (cs << 3),
            ldsb + l * 8192 + (t >> 6) * 1024 + (t & 63) * 16);
    }
}

template<int MODE, int MFAST>
__global__ __launch_bounds__(512, 2)
void gemm256(const bf16* __restrict__ A, int lda, long sA,
             const bf16* __restrict__ Bt, int ldb, long sB,
             void* __restrict__ Cp, int ldc, long sC, int K,
             const float* __restrict__ bias,
             void* __restrict__ aux1, void* __restrict__ aux2)
{
    __shared__ __align__(16) bf16 smem[65536];   // A[2][256][64] | B[2][256][64]
    char* smemB = (char*)smem;
    int bx, by, bz;
    {
        const int gx = gridDim.x, gy = gridDim.y;
        const int nwg = gx * gy * gridDim.z;
        int lid = blockIdx.x + gx * (blockIdx.y + gy * blockIdx.z);
        const int cpx = nwg >> 3;
        int swz = (lid & 7) * cpx + (lid >> 3);
        if constexpr (MFAST) {
            by = swz % gy; swz /= gy;
            bx = swz % gx;
            bz = swz / gx;
        } else {
            bx = swz % gx; swz /= gx;
            by = swz % gy;
            bz = swz / gy;
        }
    }
    const bf16* Ab = A + (long)bz * sA + (long)by * 256 * lda;
    const bf16* Bb = Bt + (long)bz * sB + (long)bx * 256 * ldb;
    const int t = threadIdx.x, lane = t & 63, wid = t >> 6;
    const int wm = wid >> 2, wn = wid & 3;      // 2 x 4 wave grid
    const int lg = lane >> 4, lr = lane & 15;

    f32x4 acc[8][4];
#pragma unroll
    for (int m = 0; m < 8; ++m)
#pragma unroll
        for (int n = 0; n < 4; ++n) acc[m][n] = (f32x4){0.f, 0.f, 0.f, 0.f};

    const int T = K >> 6;
    // prologue: stage tile 0 into dbuf 0  (B h0, B h1, A h0, A h1)
    stage_ht(Bb, ldb, 0, smemB + 65536, t);
    stage_ht(Bb + (long)128 * ldb, ldb, 0, smemB + 65536 + 16384, t);
    stage_ht(Ab, lda, 0, smemB, t);
    stage_ht(Ab + (long)128 * lda, lda, 0, smemB + 16384, t);

    for (int tt = 0; tt < T; ++tt) {
        const int cur = tt & 1, nb = cur ^ 1;
        const int ktn = (tt + 1) << 6;
        const bool pf = (tt + 1 < T);
        const int aco = cur ? 16384 : 0;          // A elems offset
        const int bco = 32768 + (cur ? 16384 : 0);
        const int anb = nb ? 32768 : 0;           // bytes
        const int bnb = 65536 + (nb ? 32768 : 0);

        bh8 afA[4], afB[4], bfA[4], bfB[4];

        // ---- phase A: quad (mh=0, kk=0); stage next B h0; tile-start sync
        if (pf) stage_ht(Bb, ldb, ktn, smemB + bnb, t);
        if (pf) asm volatile("s_waitcnt vmcnt(2)" ::: "memory");
        else    asm volatile("s_waitcnt vmcnt(0)" ::: "memory");
        __builtin_amdgcn_s_barrier();
#pragma unroll
        for (int m = 0; m < 4; ++m) {
            const int row = wm * 128 + m * 16 + lr;
            afA[m] = *(const bh8*)(smem + aco + row * 64 + (lg ^ (row & 7)) * 8);
        }
#pragma unroll
        for (int n = 0; n < 4; ++n) {
            const int row = wn * 64 + n * 16 + lr;
            bfA[n] = *(const bh8*)(smem + bco + row * 64 + (lg ^ (row & 7)) * 8);
        }
        asm volatile("s_waitcnt lgkmcnt(0)" ::: "memory");
        __builtin_amdgcn_sched_barrier(0);
        __builtin_amdgcn_s_setprio(1);
#pragma unroll
        for (int m = 0; m < 4; ++m)
#pragma unroll
            for (int n = 0; n < 4; ++n)
                acc[m][n] = __builtin_amdgcn_mfma_f32_16x16x32_bf16(afA[m], bfA[n], acc[m][n], 0, 0, 0);
        __builtin_amdgcn_s_setprio(0);
        __builtin_amdgcn_s_barrier();

        // ---- phase B: quad (mh=1, kk=0); stage next B h1
#pragma unroll
        for (int m = 0; m < 4; ++m) {
            const int row = wm * 128 + 64 + m * 16 + lr;
            afB[m] = *(const bh8*)(smem + aco + row * 64 + (lg ^ (row & 7)) * 8);
        }
        if (pf) stage_ht(Bb + (long)128 * ldb, ldb, ktn, smemB + bnb + 16384, t);
        asm volatile("s_waitcnt lgkmcnt(0)" ::: "memory");
        __builtin_amdgcn_sched_barrier(0);
        __builtin_amdgcn_s_setprio(1);
#pragma unroll
        for (int m = 0; m < 4; ++m)
#pragma unroll
            for (int n = 0; n < 4; ++n)
                acc[4 + m][n] = __builtin_amdgcn_mfma_f32_16x16x32_bf16(afB[m], bfA[n], acc[4 + m][n], 0, 0, 0);
        __builtin_amdgcn_s_setprio(0);
        __builtin_amdgcn_s_barrier();

        // ---- phase C: quad (mh=0, kk=1); stage next A h0
#pragma unroll
        for (int m = 0; m < 4; ++m) {
            const int row = wm * 128 + m * 16 + lr;
            afA[m] = *(const bh8*)(smem + aco + row * 64 + ((4 + lg) ^ (row & 7)) * 8);
        }
#pragma unroll
        for (int n = 0; n < 4; ++n) {
            const int row = wn * 64 + n * 16 + lr;
            bfB[n] = *(const bh8*)(smem + bco + row * 64 + ((4 + lg) ^ (row & 7)) * 8);
        }
        if (pf) stage_ht(Ab, lda, ktn, smemB + anb, t);
        asm volatile("s_waitcnt lgkmcnt(0)" ::: "memory");
        __builtin_amdgcn_sched_barrier(0);
        __builtin_amdgcn_s_setprio(1);
#pragma unroll
        for (int m = 0; m < 4; ++m)
#pragma unroll
            for (int n = 0; n < 4; ++n)
                acc[m][n] = __builtin_amdgcn_mfma_f32_16x16x32_bf16(afA[m], bfB[n], acc[m][n], 0, 0, 0);
        __builtin_amdgcn_s_setprio(0);
        __builtin_amdgcn_s_barrier();

        // ---- phase D: quad (mh=1, kk=1); stage next A h1
#pragma unroll
        for (int m = 0; m < 4; ++m) {
            const int row = wm * 128 + 64 + m * 16 + lr;
            afB[m] = *(const bh8*)(smem + aco + row * 64 + ((4 + lg) ^ (row & 7)) * 8);
        }
        if (pf) stage_ht(Ab + (long)128 * lda, lda, ktn, smemB + anb + 16384, t);
        asm volatile("s_waitcnt lgkmcnt(0)" ::: "memory");
        __builtin_amdgcn_sched_barrier(0);
        __builtin_amdgcn_s_setprio(1);
#pragma unroll
        for (int m = 0; m < 4; ++m)
#pragma unroll
            for (int n = 0; n < 4; ++n)
                acc[4 + m][n] = __builtin_amdgcn_mfma_f32_16x16x32_bf16(afB[m], bfB[n], acc[4 + m][n], 0, 0, 0);
        __builtin_amdgcn_s_setprio(0);
        __builtin_amdgcn_s_barrier();
    }

    // epilogue
    const int gr0 = by * 256 + wm * 128;
    const int gc0 = bx * 256 + wn * 64;
    if constexpr (MODE == 0) {                  // QKV: by 0-1 q(exp), 2-3 k, 4-5 v
        const int which = by >> 1;
        bf16* dst = (which == 0) ? (bf16*)Cp : (which == 1) ? (bf16*)aux1 : (bf16*)aux2;
        dst += (long)bz * sC;
#pragma unroll
        for (int m = 0; m < 8; ++m)
#pragma unroll
            for (int n = 0; n < 4; ++n) {
                const int col = gc0 + n * 16 + lr;
#pragma unroll
                for (int r = 0; r < 4; ++r) {
                    const int grow = gr0 + m * 16 + lg * 4 + r;
                    float v = acc[m][n][r] + bias[grow];
                    if (which == 0) v = __expf(v);
                    dst[(long)(grow - which * 512) * ldc + col] = __float2bfloat16(v);
                }
            }
    } else {                                    // fc1: bf16 out, bias[col]
        bf16* dst = (bf16*)Cp + (long)bz * sC;
#pragma unroll
        for (int m = 0; m < 8; ++m)
#pragma unroll
            for (int n = 0; n < 4; ++n) {
                const int col = gc0 + n * 16 + lr;
                const float bc = bias[col];
#pragma unroll
                for (int r = 0; r < 4; ++r) {
                    const int grow = gr0 + m * 16 + lg * 4 + r;
                    dst[(long)grow * ldc + col] = __float2bfloat16(acc[m][n][r] + bc);
                }
            }
    }
}

// ---------------------------------------------------------------- GEMM (NT) 128^2
enum { EP_BF16_BROW = 1, EP_ATTN = 3, EP_BF16_BCOL = 4, EP_OUT = 5 };

template<int MODE, int TM, int MFAST>
__global__ __launch_bounds__(256)
void gemm_bt(const bf16* __restrict__ A, int lda, long sA,
             const bf16* __restrict__ Bt, int ldb, long sB,
             void* __restrict__ Cp, int ldc, long sC, int K,
             const float* __restrict__ bias,
             const void* __restrict__ aux1, long sAux1,
             const void* __restrict__ aux2, long sAux2)
{
    constexpr int MF = TM / 32;
    __shared__ __align__(16) bf16 smem[TM * 64 + 128 * 64];
    bf16* As = smem;
    bf16* Bs = smem + TM * 64;
    int bx, by, bz;
    {
        const int gx = gridDim.x, gy = gridDim.y;
        const int nwg = gx * gy * gridDim.z;
        int lid = blockIdx.x + gx * (blockIdx.y + gy * blockIdx.z);
        const int cpx = nwg >> 3;
        int swz = (lid & 7) * cpx + (lid >> 3);
        if constexpr (MFAST) {
            by = swz % gy; swz /= gy;
            bx = swz % gx;
            bz = swz / gx;
        } else {
            bx = swz % gx; swz /= gx;
            by = swz % gy;
            bz = swz / gy;
        }
    }
    const bf16* Ab = A + (long)bz * sA + (long)by * TM * lda;
    const bf16* Bb = Bt + (long)bz * sB + (long)bx * 128 * ldb;
    const int t = threadIdx.x, lane = t & 63, wid = t >> 6;
    const int wm = wid >> 1, wn = wid & 1, lg = lane >> 4, lr = lane & 15;

    f32x4 acc[MF][4];
#pragma unroll
    for (int m = 0; m < MF; ++m)
#pragma unroll
        for (int n = 0; n < 4; ++n) acc[m][n] = (f32x4){0.f, 0.f, 0.f, 0.f};

    for (int kt = 0; kt < K; kt += 64) {
#pragma unroll
        for (int i = 0; i < MF; ++i) {
            const int ch = i * 256 + t;
            const int row = ch >> 3;
            const int cs = (ch & 7) ^ (row & 7);
            GLL(Ab + (long)row * lda + kt + (cs << 3), (char*)As + i * 4096 + wid * 1024);
        }
#pragma unroll
        for (int i = 0; i < 4; ++i) {
            const int ch = i * 256 + t;
            const int row = ch >> 3;
            const int cs = (ch & 7) ^ (row & 7);
            GLL(Bb + (long)row * ldb + kt + (cs << 3), (char*)Bs + i * 4096 + wid * 1024);
        }
        __syncthreads();
#pragma unroll
        for (int kk = 0; kk < 2; ++kk) {
            bh8 af[MF], bfv[4];
#pragma unroll
            for (int m = 0; m < MF; ++m) {
                const int row = wm * (TM / 2) + m * 16 + lr;
                const int kc = (kk * 4 + lg) ^ (row & 7);
                af[m] = *(const bh8*)(As + row * 64 + kc * 8);
            }
#pragma unroll
            for (int n = 0; n < 4; ++n) {
                const int row = wn * 64 + n * 16 + lr;
                const int kc = (kk * 4 + lg) ^ (row & 7);
                bfv[n] = *(const bh8*)(Bs + row * 64 + kc * 8);
            }
#pragma unroll
            for (int m = 0; m < MF; ++m)
#pragma unroll
                for (int n = 0; n < 4; ++n)
                    acc[m][n] = __builtin_amdgcn_mfma_f32_16x16x32_bf16(af[m], bfv[n], acc[m][n], 0, 0, 0);
        }
        __syncthreads();
    }

    const int gr0 = by * TM + wm * (TM / 2);
    const int gc0 = bx * 128 + wn * 64;
#pragma unroll
    for (int m = 0; m < MF; ++m) {
#pragma unroll
        for (int n = 0; n < 4; ++n) {
            const int gc = gc0 + n * 16 + lr;
#pragma unroll
            for (int r = 0; r < 4; ++r) {
                const int gr = gr0 + m * 16 + lg * 4 + r;
                float v = acc[m][n][r];
                if constexpr (MODE == EP_BF16_BROW) {
                    ((bf16*)Cp + (long)bz * sC)[(long)gr * ldc + gc] = __float2bfloat16(v + bias[gr]);
                } else if constexpr (MODE == EP_ATTN) {
                    const bf16* xg = (const bf16*)aux1 + (long)bz * sAux1;
                    const float* zg = (const float*)aux2 + (long)bz * sAux2;
                    ((float*)Cp + (long)bz * sC)[(long)gr * ldc + gc] =
                        zg[gr] * v + bf2f(*(const short*)(xg + (long)gr * 512 + gc));
                } else if constexpr (MODE == EP_BF16_BCOL) {
                    ((bf16*)Cp + (long)bz * sC)[(long)gr * ldc + gc] = __float2bfloat16(v + bias[gc]);
                } else { // EP_OUT
                    float* op = (float*)Cp;
                    const long idx = (long)gr * ldc + gc;
                    op[idx] = v + bias[gc] + ((const float*)aux1)[idx];
                }
            }
        }
    }
}

// ---------------------------------------------------------------- GEMM (TN, split-K x4)
__global__ __launch_bounds__(256)
void gemm_tn_splitk(const bf16* __restrict__ A, int lda, long sA,
                    const bf16* __restrict__ B, int ldb, long sB,
                    bf16* __restrict__ part)
{
    __shared__ __align__(16) short smem[2 * 64 * 128];
    short* As = smem;
    short* Bs = smem + 64 * 128;
    int bx, by, bzl;
    {
        const int gx = gridDim.x, gy = gridDim.y;
        const int nwg = gx * gy * gridDim.z;
        int lid = blockIdx.x + gx * (blockIdx.y + gy * blockIdx.z);
        const int cpx = nwg >> 3;
        int swz = (lid & 7) * cpx + (lid >> 3);
        bx = swz % gx; swz /= gx;
        by = swz % gy;
        bzl = swz / gy;
    }
    const int bz = bzl >> 2, ks = bzl & 3;
    const bf16* Ab = A + (long)bz * sA + (long)ks * 1024 * lda + by * 128;
    const bf16* Bb = B + (long)bz * sB + (long)ks * 1024 * ldb + bx * 128;
    const int t = threadIdx.x, lane = t & 63, wid = t >> 6;
    const int wm = wid >> 1, wn = wid & 1, lg = lane >> 4, lr = lane & 15;

    f32x4 acc[4][4];
#pragma unroll
    for (int m = 0; m < 4; ++m)
#pragma unroll
        for (int n = 0; n < 4; ++n) acc[m][n] = (f32x4){0.f, 0.f, 0.f, 0.f};

    for (int kt = 0; kt < 1024; kt += 64) {
#pragma unroll
        for (int i = 0; i < 4; ++i) {
            const int ch = i * 256 + t;
            const int row = ch >> 4;
            const int cs = (ch & 15) ^ (((row >> 3) & 3) << 1);
            GLL(Ab + (long)(kt + row) * lda + (cs << 3), (char*)As + i * 4096 + wid * 1024);
            GLL(Bb + (long)(kt + row) * ldb + (cs << 3), (char*)Bs + i * 4096 + wid * 1024);
        }
        __syncthreads();
#pragma unroll
        for (int kk = 0; kk < 2; ++kk) {
            bh8 af[4], bfv[4];
#pragma unroll
            for (int m = 0; m < 4; ++m) {
                const int col = wm * 64 + m * 16 + lr;
#pragma unroll
                for (int u = 0; u < 8; ++u) {
                    const int row = kk * 32 + lg * 8 + u;
                    af[m][u] = As[row * 128 + (((col >> 3) ^ (((row >> 3) & 3) << 1)) << 3) + (col & 7)];
                }
            }
#pragma unroll
            for (int n = 0; n < 4; ++n) {
                const int col = wn * 64 + n * 16 + lr;
#pragma unroll
                for (int u = 0; u < 8; ++u) {
                    const int row = kk * 32 + lg * 8 + u;
                    bfv[n][u] = Bs[row * 128 + (((col >> 3) ^ (((row >> 3) & 3) << 1)) << 3) + (col & 7)];
                }
            }
#pragma unroll
            for (int m = 0; m < 4; ++m)
#pragma unroll
                for (int n = 0; n < 4; ++n)
                    acc[m][n] = __builtin_amdgcn_mfma_f32_16x16x32_bf16(af[m], bfv[n], acc[m][n], 0, 0, 0);
        }
        __syncthreads();
    }

    bf16* Cs = (bf16*)smem;
    bf16* dstb = part + ((long)bzl << 18) + (long)by * 128 * 512;
#pragma unroll
    for (int m = 0; m < 4; ++m)
#pragma unroll
        for (int n = 0; n < 4; ++n)
#pragma unroll
            for (int r = 0; r < 4; ++r) {
                const int row = wm * 64 + m * 16 + lg * 4 + r;
                const int col = wn * 64 + n * 16 + lr;
                Cs[row * 128 + (col ^ (((row >> 2) & 3) << 4))] = __float2bfloat16(acc[m][n][r]);
            }
    __syncthreads();
#pragma unroll
    for (int it = 0; it < 8; ++it) {
        const int id = it * 256 + t;
        const int row = id >> 4, colc = (id & 15) << 3;
        bh8 v = *(const bh8*)(Cs + row * 128 + (colc ^ (((row >> 2) & 3) << 4)));
        *(bh8*)(dstb + (long)row * 512 + bx * 128 + colc) = v;
    }
}

// ---------------------------------------------------------------- merged transposes
__global__ __launch_bounds__(256)
void k_transpose3(const float* __restrict__ fc1w, bf16* __restrict__ fc1wT,
                  const float* __restrict__ fc2w, bf16* __restrict__ fc2wT,
                  const float* __restrict__ x, bf16* __restrict__ xbT)
{
    __shared__ float tile[64][65];
    const int bid = blockIdx.x;
    const float* s; bf16* d; int Rd, Cd, bx, by;
    if (bid < 256) {
        s = fc1w; d = fc1wT; Rd = 2048; Cd = 512; bx = bid & 31; by = bid >> 5;
    } else if (bid < 512) {
        const int i = bid - 256;
        s = fc2w; d = fc2wT; Rd = 512; Cd = 2048; bx = i & 7; by = i >> 3;
    } else {
        const int i = bid - 512;
        const int bz = i >> 9, j = i & 511;
        bx = j & 63; by = j >> 6;
        const long NC = (long)NDIM * CDIM;
        s = x + (long)bz * NC; d = xbT + (long)bz * NC; Rd = 4096; Cd = 512;
    }
    const int r0 = bx * 64, c0 = by * 64;
    const int t = threadIdx.x;
#pragma unroll 4
    for (int i = 0; i < 16; ++i) {
        int idx = i * 256 + t;
        int a = idx >> 6, b = idx & 63;
        tile[a][b] = s[(long)(c0 + a) * Rd + r0 + b];
    }
    __syncthreads();
#pragma unroll 4
    for (int i = 0; i < 16; ++i) {
        int idx = i * 256 + t;
        int a = idx >> 6, b = idx & 63;
        d[(long)(r0 + a) * Cd + c0 + b] = __float2bfloat16(tile[b][a]);
    }
}

// one-shot setup
__global__ void k_setup(const float* __restrict__ Wq, const float* __restrict__ Wk,
                        const float* __restrict__ Wv, bf16* __restrict__ oq,
                        bf16* __restrict__ ok, bf16* __restrict__ ov,
                        const float* __restrict__ scale, float* __restrict__ invsc,
                        const float* __restrict__ w, float* __restrict__ wT,
                        const float* __restrict__ bq, const float* __restrict__ bk,
                        const float* __restrict__ bv, float* __restrict__ bqkv) {
    int i = blockIdx.x * 256 + threadIdx.x;
    if (i < 262144) {
        oq[i] = __float2bfloat16(Wq[i]);
        ok[i] = __float2bfloat16(Wk[i]);
        ov[i] = __float2bfloat16(Wv[i]);
    }
    if (i < 512) invsc[i] = 1.0f / log1pf(expf(scale[i]));
    if (i < 1536) bqkv[i] = (i < 512 ? bq[i] : (i < 1024 ? bk[i - 512] : bv[i - 1024]));
    if (i < HIDD * 9) {
        int chn = i / 9, kk = i % 9;
        wT[kk * HIDD + chn] = w[i];
    }
}

__global__ void k_fill(float* o, int n, float v) {
    int i = blockIdx.x * 256 + threadIdx.x; if (i < n) o[i] = v;
}

// ------------------------------------------------- combined column partial sums
__global__ __launch_bounds__(256)
void k_colsums(const bf16* __restrict__ qe, const bf16* __restrict__ kb,
               float* __restrict__ qpart, float* __restrict__ kpart) {
    const int xb = blockIdx.x;
    const int ic = blockIdx.y, b = blockIdx.z;
    const int j = (xb & 1) * 256 + threadIdx.x;
    const bf16* src = (xb < 2) ? qe : kb;
    const bf16* p = src + (long)b * (NDIM * CDIM) + (long)ic * 256 * CDIM + j;
    float s = 0.f;
    for (int i = 0; i < 256; ++i) s += bf2f(*(const short*)(p + (long)i * CDIM));
    ((xb < 2) ? qpart : kpart)[((long)b * 16 + ic) * CDIM + j] = s;
}

__global__ __launch_bounds__(256)
void k_red2(const float* __restrict__ qpart, float* __restrict__ qsum,
            const float* __restrict__ kpart, float* __restrict__ ksum) {
    const int idx = blockIdx.x * 256 + threadIdx.x;
    const int which = idx >> 12, r = idx & 4095;
    const int b = r >> 9, c = r & 511;
    const float* src = which ? kpart : qpart;
    float s = 0.f;
#pragma unroll
    for (int jc = 0; jc < 16; ++jc) s += src[((long)(b * 16 + jc)) * CDIM + c];
    (which ? ksum : qsum)[r] = s;
}

// merged: bid<1024 -> kvt reduce; else q row pass + fused z
__global__ __launch_bounds__(256)
void k_kvqrow(const bf16* __restrict__ part, bf16* __restrict__ kvt,
              const bf16* __restrict__ qe, const float* __restrict__ qsum,
              const float* __restrict__ invsc, bf16* __restrict__ qb,
              const float* __restrict__ ksum, float* __restrict__ z)
{
    if (blockIdx.x < 1024) {
        const long e = ((long)blockIdx.x * 256 + threadIdx.x) * 8;
        const int b = (int)(e >> 18);
        const int off = (int)(e & 262143);
        float s[8] = {0.f, 0.f, 0.f, 0.f, 0.f, 0.f, 0.f, 0.f};
#pragma unroll
        for (int ks = 0; ks < 4; ++ks) {
            bh8 v = *(const bh8*)(part + (((long)(b * 4 + ks)) << 18) + off);
#pragma unroll
            for (int j = 0; j < 8; ++j) s[j] += bf2f(v[j]);
        }
        bh8 o;
#pragma unroll
        for (int j = 0; j < 8; ++j) o[j] = f2bf(s[j]);
        *(bh8*)(kvt + ((long)b << 18) + off) = o;
        return;
    }
    const long row = (long)(blockIdx.x - 1024) * 4 + (threadIdx.x >> 6);
    const int lane = threadIdx.x & 63;
    const int b = (int)(row >> 12);
    bh8 ev = *(const bh8*)(qe + row * CDIM + lane * 8);
    const float* qs = qsum + b * CDIM + lane * 8;
    const float* is = invsc + lane * 8;
    f32x4 s0 = *(const f32x4*)qs, s1 = *(const f32x4*)(qs + 4);
    f32x4 i0 = *(const f32x4*)is, i1 = *(const f32x4*)(is + 4);
    float q[8];
#pragma unroll
    for (int k = 0; k < 4; ++k) {
        q[k]     = (bf2f(ev[k]) / s0[k] + 1e-6f) * i0[k];
        q[k + 4] = (bf2f(ev[k + 4]) / s1[k] + 1e-6f) * i1[k];
    }
    float s2 = 0.f, s6 = 0.f, q3[8];
#pragma unroll
    for (int k = 0; k < 8; ++k) { s2 += q[k] * q[k]; float c = q[k] * q[k] * q[k]; q3[k] = c; s6 += c * c; }
    s2 = wsum(s2); s6 = wsum(s6);
    const float sc = sqrtf(s2) / sqrtf(s6);
    bh8 o;
#pragma unroll
    for (int k = 0; k < 8; ++k) o[k] = f2bf(q3[k] * sc);
    *(bh8*)(qb + row * CDIM + lane * 8) = o;
    const float* ks = ksum + (long)b * CDIM + lane * 8;
    f32x4 k0 = *(const f32x4*)ks, k1 = *(const f32x4*)(ks + 4);
    float zd = 0.f;
#pragma unroll
    for (int j = 0; j < 4; ++j) { zd += bf2f(o[j]) * k0[j]; zd += bf2f(o[j + 4]) * k1[j]; }
    zd = wsum(zd);
    if (lane == 0) z[row] = 1.0f / (zd + 1e-6f);
}

// k row pass (IN-PLACE, bf16)
__global__ __launch_bounds__(256)
void k_krow(bf16* __restrict__ kb, const float* __restrict__ invsc)
{
    const long row = (long)blockIdx.x * 4 + (threadIdx.x >> 6);
    const int lane = threadIdx.x & 63;
    bh8 v = *(const bh8*)(kb + row * CDIM + lane * 8);
    const float* is = invsc + lane * 8;
    f32x4 i0 = *(const f32x4*)is, i1 = *(const f32x4*)(is + 4);
    float xv[8];
#pragma unroll
    for (int k = 0; k < 8; ++k) xv[k] = bf2f(v[k]);
    float mx = -1e30f;
#pragma unroll
    for (int k = 0; k < 8; ++k) mx = fmaxf(mx, xv[k]);
    mx = wmax(mx);
    float e[8], se = 0.f;
#pragma unroll
    for (int k = 0; k < 8; ++k) { e[k] = __expf(xv[k] - mx); se += e[k]; }
    se = wsum(se);
    const float inv = 1.0f / se;
    float q[8];
#pragma unroll
    for (int k = 0; k < 4; ++k) {
        q[k]     = (e[k] * inv + 1e-6f) * i0[k];
        q[k + 4] = (e[k + 4] * inv + 1e-6f) * i1[k];
    }
    float s2 = 0.f, s6 = 0.f, q3[8];
#pragma unroll
    for (int k = 0; k < 8; ++k) { s2 += q[k] * q[k]; float c = q[k] * q[k] * q[k]; q3[k] = c; s6 += c * c; }
    s2 = wsum(s2); s6 = wsum(s6);
    const float sc = sqrtf(s2) / sqrtf(s6);
    bh8 o;
#pragma unroll
    for (int k = 0; k < 8; ++k) o[k] = f2bf(q3[k] * sc);
    *(bh8*)(kb + row * CDIM + lane * 8) = o;
}

// LN over 512
__global__ __launch_bounds__(256)
void k_ln512(const float* __restrict__ src, const float* __restrict__ g,
             const float* __restrict__ bta, bf16* __restrict__ dst)
{
    const long row = (long)blockIdx.x * 4 + (threadIdx.x >> 6);
    const int lane = threadIdx.x & 63;
    const float* p = src + row * CDIM + lane * 8;
    f32x4 a0 = *(const f32x4*)p, a1 = *(const f32x4*)(p + 4);
    float s = 0.f, ss = 0.f;
#pragma unroll
    for (int k = 0; k < 4; ++k) { s += a0[k] + a1[k]; ss += a0[k] * a0[k] + a1[k] * a1[k]; }
    s = wsum(s); ss = wsum(ss);
    const float mean = s * (1.0f / 512), var = ss * (1.0f / 512) - mean * mean;
    const float rstd = rsqrtf(var + 1e-5f);
    const float* gp = g + lane * 8;
    const float* bp = bta + lane * 8;
    f32x4 g0 = *(const f32x4*)gp, g1 = *(const f32x4*)(gp + 4);
    f32x4 b0 = *(const f32x4*)bp, b1 = *(const f32x4*)(bp + 4);
    bh8 o;
#pragma unroll
    for (int k = 0; k < 4; ++k) {
        o[k]     = f2bf((a0[k] - mean) * rstd * g0[k] + b0[k]);
        o[k + 4] = f2bf((a1[k] - mean) * rstd * g1[k] + b1[k]);
    }
    *(bh8*)(dst + row * CDIM + lane * 8) = o;
}

// depthwise 3x3 + skip + LN(2048) + exact GELU
__global__ __launch_bounds__(256)
void k_dwlngelu4(const bf16* __restrict__ a, const float* __restrict__ dwwT,
                 const float* __restrict__ dwb, const float* __restrict__ g1,
                 const float* __restrict__ b1, bf16* __restrict__ ax)
{
    const long s0 = (long)blockIdx.x * 4;
    const int h = (int)((s0 >> 6) & 63);
    const int w0 = (int)(s0 & 63);
    const int ch = threadIdx.x * 8;

    float wgt[9][8];
#pragma unroll
    for (int kk = 0; kk < 9; ++kk) {
        f32x4 w0v = *(const f32x4*)(dwwT + kk * HIDD + ch);
        f32x4 w1v = *(const f32x4*)(dwwT + kk * HIDD + ch + 4);
#pragma unroll
        for (int j = 0; j < 4; ++j) { wgt[kk][j] = w0v[j]; wgt[kk][j + 4] = w1v[j]; }
    }
#pragma unroll
    for (int j = 0; j < 8; ++j) wgt[4][j] += 1.0f;

    float acc[4][8];
    {
        f32x4 d0 = *(const f32x4*)(dwb + ch), d1 = *(const f32x4*)(dwb + ch + 4);
#pragma unroll
        for (int ti = 0; ti < 4; ++ti)
#pragma unroll
            for (int j = 0; j < 4; ++j) { acc[ti][j] = d0[j]; acc[ti][j + 4] = d1[j]; }
    }

#pragma unroll
    for (int dy = -1; dy <= 1; ++dy) {
        const int hh = h + dy;
        if ((unsigned)hh >= 64u) continue;
#pragma unroll
        for (int c = -1; c <= 4; ++c) {
            const int ww = w0 + c;
            if ((unsigned)ww >= 64u) continue;
            bh8 v = *(const bh8*)(a + (s0 + (long)dy * 64 + c) * HIDD + ch);
            float f[8];
#pragma unroll
            for (int j = 0; j < 8; ++j) f[j] = bf2f(v[j]);
#pragma unroll
            for (int ti = 0; ti < 4; ++ti) {
                const int dx = c - ti;
                if (dx < -1 || dx > 1) continue;
                const int kk = (dy + 1) * 3 + (dx + 1);
#pragma unroll
                for (int j = 0; j < 8; ++j) acc[ti][j] += wgt[kk][j] * f[j];
            }
        }
    }

    float sv[4], qv[4];
#pragma unroll
    for (int ti = 0; ti < 4; ++ti) {
        float s = 0.f, q = 0.f;
#pragma unroll
        for (int j = 0; j < 8; ++j) { s += acc[ti][j]; q += acc[ti][j] * acc[ti][j]; }
        sv[ti] = wsum(s); qv[ti] = wsum(q);
    }
    __shared__ float red[4][4][2];
    const int wid = threadIdx.x >> 6, lane = threadIdx.x & 63;
    if (lane == 0)
#pragma unroll
        for (int ti = 0; ti < 4; ++ti) { red[wid][ti][0] = sv[ti]; red[wid][ti][1] = qv[ti]; }
    __syncthreads();

    f32x4 ga = *(const f32x4*)(g1 + ch), gb = *(const f32x4*)(g1 + ch + 4);
    f32x4 ba = *(const f32x4*)(b1 + ch), bb = *(const f32x4*)(b1 + ch + 4);
    float gg[8], bb8[8];
#pragma unroll
    for (int j = 0; j < 4; ++j) { gg[j] = ga[j]; gg[j + 4] = gb[j]; bb8[j] = ba[j]; bb8[j + 4] = bb[j]; }

#pragma unroll
    for (int ti = 0; ti < 4; ++ti) {
        const float s = red[0][ti][0] + red[1][ti][0] + red[2][ti][0] + red[3][ti][0];
        const float q = red[0][ti][1] + red[1][ti][1] + red[2][ti][1] + red[3][ti][1];
        const float mean = s * (1.0f / 2048), var = q * (1.0f / 2048) - mean * mean;
        const float rstd = rsqrtf(var + 1e-5f);
        bh8 o;
#pragma unroll
        for (int j = 0; j < 8; ++j) {
            float y = (acc[ti][j] - mean) * rstd * gg[j] + bb8[j];
            o[j] = f2bf(0.5f * y * (1.0f + erff(y * 0.70710678118654752f)));
        }
        *(bh8*)(ax + (s0 + ti) * HIDD + ch) = o;
    }
}

// ---------------------------------------------------------------- launch
extern "C" void kernel_launch(void* const* d_in, const int* in_sizes, int n_in,
                              void* d_out, int out_size, void* d_ws, size_t ws_size,
                              hipStream_t stream) {
    const float* x     = (const float*)d_in[0];
    const float* Wq    = (const float*)d_in[1];
    const float* bq    = (const float*)d_in[2];
    const float* Wk    = (const float*)d_in[3];
    const float* bk    = (const float*)d_in[4];
    const float* Wv    = (const float*)d_in[5];
    const float* bv    = (const float*)d_in[6];
    const float* scale = (const float*)d_in[7];
    const float* fc1_w = (const float*)d_in[8];
    const float* fc1_b = (const float*)d_in[9];
    const float* dw_w  = (const float*)d_in[10];
    const float* dw_b  = (const float*)d_in[11];
    const float* fc2_w = (const float*)d_in[12];
    const float* fc2_b = (const float*)d_in[13];
    const float* ln1_g = (const float*)d_in[14];
    const float* ln1_b = (const float*)d_in[15];
    const float* lnm_g = (const float*)d_in[16];
    const float* lnm_b = (const float*)d_in[17];
    float* out = (float*)d_out;
    char* p = (char*)d_ws;

    bf16*  xbT   = (bf16*)(p + 0);
    bf16*  kb    = (bf16*)(p + 33554432);
    bf16*  vb    = (bf16*)(p + 67108864);
    bf16*  kvt   = (bf16*)(p + 100663296);
    bf16*  wqb   = (bf16*)(p + 104857600);
    bf16*  wkb   = (bf16*)(p + 105381888);
    bf16*  wvb   = (bf16*)(p + 105906176);
    bf16*  fc1wT = (bf16*)(p + 106430464);
    bf16*  fc2wT = (bf16*)(p + 108527616);
    float* invsc = (float*)(p + 110624768);
    float* dwwT  = (float*)(p + 110626816);
    float* bqkv  = (float*)(p + 110700544);
    float* qsum  = (float*)(p + 110757888);
    float* ksum  = (float*)(p + 110905344);
    float* zbuf  = (float*)(p + 110921728);
    const size_t REQUIRED = 111052800;
    float* qpart = (float*)kvt;
    float* kpart = (float*)((char*)kvt + 262144);
    bf16*  qe    = (bf16*)out;
    bf16*  kvpart= (bf16*)((char*)out + 33554432);
    bf16*  qb    = kb;
    bf16*  abuf  = (bf16*)(p + 0);
    bf16*  axbuf = (bf16*)(p + 33554432);
    bf16*  tbuf  = (bf16*)(p + 67108864);

    if (ws_size < REQUIRED) {
        k_fill<<<(out_size + 255) / 256, 256, 0, stream>>>(out, out_size, 100000.0f + (float)(ws_size >> 20));
        return;
    }

    const long NC = (long)NDIM * CDIM;

    k_setup<<<1024, 256, 0, stream>>>(Wq, Wk, Wv, wqb, wkb, wvb, scale, invsc,
                                      dw_w, dwwT, bq, bk, bv, bqkv);
    k_transpose3<<<4608, 256, 0, stream>>>(fc1_w, fc1wT, fc2_w, fc2wT, x, xbT);

    // fused conv q/k/v: 256^2 8-phase pipelined GEMM (512 thr, counted vmcnt)
    gemm256<0, 1><<<dim3(16, 6, 8), 512, 0, stream>>>(
        wqb, 512, 0, xbT, 512, NC, qe, 4096, NC, 512, bqkv, kb, vb);

    k_krow<<<8192, 256, 0, stream>>>(kb, invsc);
    k_colsums<<<dim3(4, 16, 8), 256, 0, stream>>>(qe, kb, qpart, kpart);
    k_red2<<<32, 256, 0, stream>>>(qpart, qsum, kpart, ksum);

    gemm_tn_splitk<<<dim3(4, 4, 32), 256, 0, stream>>>(vb, 512, NC, kb, 512, NC, kvpart);
    k_kvqrow<<<9216, 256, 0, stream>>>(kvpart, kvt, qe, qsum, invsc, qb, ksum, zbuf);

    gemm_bt<EP_ATTN, 128, 0><<<dim3(4, 32, 8), 256, 0, stream>>>(
        qb, 512, NC, kvt, 512, 262144, out, 512, NC, 512, nullptr, xbT, NC, zbuf, 4096);

    k_ln512<<<8192, 256, 0, stream>>>(out, lnm_g, lnm_b, tbuf);
    for (int q4 = 0; q4 < 4; ++q4) {
        float* outq = out + (long)q4 * 8192 * CDIM;
        bf16* tq = tbuf + (long)q4 * 8192 * CDIM;
        // fc1: 256^2 8-phase pipelined GEMM (256 blocks = 1/CU)
        gemm256<1, 0><<<dim3(8, 32, 1), 512, 0, stream>>>(
            tq, 512, 0, fc1wT, 512, 0, abuf, 2048, 0, 512, fc1_b, nullptr, nullptr);
        k_dwlngelu4<<<2048, 256, 0, stream>>>(abuf, dwwT, dw_b, ln1_g, ln1_b, axbuf);
        gemm_bt<EP_OUT, 64, 0><<<dim3(4, 128, 1), 256, 0, stream>>>(
            axbuf, 2048, 0, fc2wT, 2048, 0, outq, 512, 0, 2048, fc2_b, outq, 0, nullptr, 0);
    }
}